// Round 1
// baseline (513.646 us; speedup 1.0000x reference)
//
#include <hip/hip_runtime.h>

typedef _Float16 f16;
typedef _Float16 half8 __attribute__((ext_vector_type(8)));
typedef float float4v __attribute__((ext_vector_type(4)));

#define NE 768
#define TT 4096
#define NB 4
#define MM (NB*TT)
#define SPAN 256
#define JW 320   // 5 key-tiles of 64 cover j in [qt*64-256, qt*64+64)

__device__ __forceinline__ float gelu_exact(float v){
  return 0.5f * v * (1.0f + erff(v * 0.70710678118654752440f));
}

// ---------- fp32 -> fp16 convert ----------
__global__ __launch_bounds__(256) void cvt_f16_k(const float* __restrict__ in,
                                                 f16* __restrict__ out, int n){
  int i = (blockIdx.x*256 + threadIdx.x)*4;
  if (i >= n) return;
  float4 v = *(const float4*)(in + i);
  struct alignas(8) H4 { f16 a,b,c,d; };
  H4 o; o.a=(f16)v.x; o.b=(f16)v.y; o.c=(f16)v.z; o.d=(f16)v.w;
  *(H4*)(out + i) = o;
}

// ---------- W[k][n] fp32 -> Wt[n][k] fp16 ----------
__global__ __launch_bounds__(256) void transpose_w_k(const float* __restrict__ W,
                                                     f16* __restrict__ Wt){
  __shared__ float tile[32][33];
  int tx = threadIdx.x & 31, ty = threadIdx.x >> 5;   // 32 x 8
  int bx = blockIdx.x * 32, by = blockIdx.y * 32;
  #pragma unroll
  for (int r=0;r<32;r+=8) tile[ty+r][tx] = W[(size_t)(by+ty+r)*NE + bx + tx];
  __syncthreads();
  #pragma unroll
  for (int r=0;r<32;r+=8) Wt[(size_t)(bx+ty+r)*NE + by + tx] = (f16)tile[tx][ty+r];
}

// ---------- fused MLP GEMM: Out = [gelu](A @ Bt^T + bias) ----------
// A: [MM][NE] f16 row-major. Bt: [NE(out)][NE(in)] f16 (pre-transposed weight).
// TRANSV=false: Out f16 row-major [MM][NE].
// TRANSV=true : Out = vt[b][d][t] f16 (transposed store for the PV B-operand).
template<bool GELU, bool TRANSV>
__global__ __launch_bounds__(256) void gemm_mlp_k(
    const f16* __restrict__ A, const f16* __restrict__ Bt,
    const float* __restrict__ bias, f16* __restrict__ Out)
{
  __shared__ f16 smem[128*136];           // union: staging 2*128*40 | Ct 128*136
  f16* As = smem;
  f16* Bs = smem + 128*40;
  const int tid  = threadIdx.x;
  const int lane = tid & 63, wave = tid >> 6;
  const int l15 = lane & 15, lk = lane >> 4;
  const int wr = (wave >> 1)*64, wc = (wave & 1)*64;
  const int brow = blockIdx.x * 128, bcol = blockIdx.y * 128;

  float4v acc[4][4]{};

  for (int k0 = 0; k0 < NE; k0 += 32){
    #pragma unroll
    for (int it=0; it<2; ++it){
      int idx = tid + it*256;             // 0..511
      int r = idx >> 2, c = (idx & 3)*8;  // row 0..127, k-chunk of 8
      *(half8*)&As[r*40 + c] = *(const half8*)(A  + (size_t)(brow + r)*NE + k0 + c);
      *(half8*)&Bs[r*40 + c] = *(const half8*)(Bt + (size_t)(bcol + r)*NE + k0 + c);
    }
    __syncthreads();
    half8 af[4], bf[4];
    #pragma unroll
    for (int i=0;i<4;++i) af[i] = *(const half8*)&As[(wr + i*16 + l15)*40 + lk*8];
    #pragma unroll
    for (int i=0;i<4;++i) bf[i] = *(const half8*)&Bs[(wc + i*16 + l15)*40 + lk*8];
    #pragma unroll
    for (int i=0;i<4;++i)
      #pragma unroll
      for (int j=0;j<4;++j)
        acc[i][j] = __builtin_amdgcn_mfma_f32_16x16x32_f16(af[i], bf[j], acc[i][j], 0, 0, 0);
    __syncthreads();
  }

  if (!TRANSV){
    #pragma unroll
    for (int i=0;i<4;++i){
      #pragma unroll
      for (int j=0;j<4;++j){
        int col = bcol + wc + j*16 + l15;
        float bv = bias[col];
        #pragma unroll
        for (int r=0;r<4;++r){
          int row = brow + wr + i*16 + lk*4 + r;
          float v = acc[i][j][r] + bv;
          if (GELU) v = gelu_exact(v);
          Out[(size_t)row*NE + col] = (f16)v;
        }
      }
    }
  } else {
    // write C tile transposed into LDS, then coalesced store to vt[b][d][t]
    #pragma unroll
    for (int i=0;i<4;++i){
      #pragma unroll
      for (int j=0;j<4;++j){
        int cl = wc + j*16 + l15;          // local col (d)
        float bv = bias[bcol + cl];
        #pragma unroll
        for (int r=0;r<4;++r){
          int rl = wr + i*16 + lk*4 + r;   // local row (t)
          float v = acc[i][j][r] + bv;
          if (GELU) v = gelu_exact(v);
          smem[cl*136 + rl] = (f16)v;
        }
      }
    }
    __syncthreads();
    int b = brow / TT, t0 = brow % TT;     // 4096 % 128 == 0: tiles never cross batch
    #pragma unroll
    for (int it=0; it<8; ++it){
      int idx = tid + it*256;              // 0..2047
      int c = idx >> 4, rr = (idx & 15)*8;
      half8 v = *(const half8*)&smem[c*136 + rr];
      *(half8*)(Out + (size_t)b*NE*TT + (size_t)(bcol + c)*TT + t0 + rr) = v;
    }
  }
}

// ---------- banded QK^T: S[row][c] = mask * (q_row . k_{jbase+c}) / SCALE ----------
__global__ __launch_bounds__(256) void attn_qk_k(
    const f16* __restrict__ Q, const f16* __restrict__ K, f16* __restrict__ S)
{
  __shared__ f16 Ks[JW*40];
  const int tid = threadIdx.x, lane = tid & 63, wave = tid >> 6;
  const int l15 = lane & 15, lk = lane >> 4;
  const int qt = blockIdx.x, b = blockIdx.y;
  const int rowbase = b*TT + qt*64;
  const int jbase = qt*64 - SPAN;
  const int qrow = rowbase + wave*16;

  float4v acc[20]{};

  for (int k0 = 0; k0 < NE; k0 += 32){
    #pragma unroll
    for (int it=0; it<5; ++it){
      int idx = tid + it*256;              // 0..1279
      int r = idx >> 2, c = (idx & 3)*8;   // j-row 0..319
      int j = jbase + r;
      half8 v{};
      if (j >= 0) v = *(const half8*)(K + (size_t)(b*TT + j)*NE + k0 + c);
      *(half8*)&Ks[r*40 + c] = v;
    }
    __syncthreads();
    half8 aq = *(const half8*)(Q + (size_t)(qrow + l15)*NE + k0 + lk*8);
    #pragma unroll
    for (int f=0; f<20; ++f){
      half8 bk = *(const half8*)&Ks[(f*16 + l15)*40 + lk*8];
      acc[f] = __builtin_amdgcn_mfma_f32_16x16x32_f16(aq, bk, acc[f], 0, 0, 0);
    }
    __syncthreads();
  }
  const float inv = 1.0f / 443.40500673763256f;  // 1/sqrt(768*256)
  #pragma unroll
  for (int f=0; f<20; ++f){
    int c = f*16 + l15;
    int jg = jbase + c;
    #pragma unroll
    for (int r=0;r<4;++r){
      int iloc = wave*16 + lk*4 + r;
      int d = (qt*64 + iloc) - jg;
      float v = (d >= 0 && d < SPAN) ? acc[f][r]*inv : 0.0f;
      S[(size_t)(rowbase + iloc)*JW + c] = (f16)v;
    }
  }
}

// ---------- PV: Y[row][d] = sum_j S[row][j] * V[j][d], V given transposed ----------
__global__ __launch_bounds__(256) void attn_pv_k(
    const f16* __restrict__ S, const f16* __restrict__ Vt, float* __restrict__ Y)
{
  __shared__ f16 Vs[64*328];
  const int tid = threadIdx.x, lane = tid & 63, wave = tid >> 6;
  const int l15 = lane & 15, lk = lane >> 4;
  const int qt = blockIdx.x, dc = blockIdx.y, b = blockIdx.z;
  const int d0 = dc*64;
  const int jbase = qt*64 - SPAN;
  const int rowbase = b*TT + qt*64;

  #pragma unroll
  for (int it=0; it<10; ++it){
    int idx = tid + it*256;                // 0..2559
    int dd = idx / 40;
    int c = (idx - dd*40)*8;               // j-offset 0..312
    int j = jbase + c;                     // chunk of 8 shares sign (jbase%64==0, c%8==0)
    half8 v{};
    if (j >= 0) v = *(const half8*)(Vt + ((size_t)b*NE + d0 + dd)*TT + j);
    *(half8*)&Vs[dd*328 + c] = v;
  }
  __syncthreads();

  float4v acc[4]{};
  const f16* srow = S + (size_t)(rowbase + wave*16 + l15)*JW;
  #pragma unroll
  for (int kt = 0; kt < JW; kt += 32){
    half8 as = *(const half8*)(srow + kt + lk*8);
    #pragma unroll
    for (int nf=0; nf<4; ++nf){
      half8 bv = *(const half8*)&Vs[(nf*16 + l15)*328 + kt + lk*8];
      acc[nf] = __builtin_amdgcn_mfma_f32_16x16x32_f16(as, bv, acc[nf], 0, 0, 0);
    }
  }
  #pragma unroll
  for (int nf=0; nf<4; ++nf){
    #pragma unroll
    for (int r=0;r<4;++r){
      int row = rowbase + wave*16 + lk*4 + r;
      Y[(size_t)row*NE + d0 + nf*16 + l15] = acc[nf][r];
    }
  }
}

// ---------- LayerNorm over last dim (768), one wave per row ----------
__global__ __launch_bounds__(256) void layernorm_k(
    const float* __restrict__ Y, const float* __restrict__ g,
    const float* __restrict__ be, float* __restrict__ Out)
{
  int row  = blockIdx.x*4 + (threadIdx.x >> 6);
  int lane = threadIdx.x & 63;
  const float* y = Y + (size_t)row*NE;
  float v[12], s=0.f, s2=0.f;
  #pragma unroll
  for (int i=0;i<12;++i){ v[i] = y[lane + i*64]; s += v[i]; s2 += v[i]*v[i]; }
  #pragma unroll
  for (int m=32;m>=1;m>>=1){ s += __shfl_xor(s,m,64); s2 += __shfl_xor(s2,m,64); }
  float mu  = s*(1.f/NE);
  float var = s2*(1.f/NE) - mu*mu;
  float rs  = rsqrtf(var + 1e-5f);
  float* o = Out + (size_t)row*NE;
  #pragma unroll
  for (int i=0;i<12;++i){ int c = lane + i*64; o[c] = (v[i]-mu)*rs*g[c] + be[c]; }
}

extern "C" void kernel_launch(void* const* d_in, const int* in_sizes, int n_in,
                              void* d_out, int out_size, void* d_ws, size_t ws_size,
                              hipStream_t stream)
{
  (void)in_sizes; (void)n_in; (void)out_size; (void)ws_size;
  const float* x     = (const float*)d_in[0];
  const float* w1[3] = {(const float*)d_in[1], (const float*)d_in[5], (const float*)d_in[9]};
  const float* b1[3] = {(const float*)d_in[2], (const float*)d_in[6], (const float*)d_in[10]};
  const float* w2[3] = {(const float*)d_in[3], (const float*)d_in[7], (const float*)d_in[11]};
  const float* b2[3] = {(const float*)d_in[4], (const float*)d_in[8], (const float*)d_in[12]};
  const float* lnw = (const float*)d_in[13];
  const float* lnb = (const float*)d_in[14];

  char* ws = (char*)d_ws;
  size_t off = 0;
  auto alloc = [&](size_t bytes)->void* {
    void* p = ws + off; off += (bytes + 255) & ~size_t(255); return p;
  };
  f16* xh = (f16*)alloc((size_t)MM*NE*2);
  f16* H  = (f16*)alloc((size_t)MM*NE*2);
  f16* qh = (f16*)alloc((size_t)MM*NE*2);
  f16* kh = (f16*)alloc((size_t)MM*NE*2);
  f16* vt = (f16*)alloc((size_t)MM*NE*2);      // [NB][NE][TT]
  f16 *wt1[3], *wt2[3];
  for (int i=0;i<3;++i){ wt1[i]=(f16*)alloc((size_t)NE*NE*2); wt2[i]=(f16*)alloc((size_t)NE*NE*2); }
  f16*   sb = (f16*)alloc((size_t)MM*JW*2);    // banded scores [MM][320]
  float* y  = (float*)alloc((size_t)MM*NE*4);  // total ~194 MB of ws

  cvt_f16_k<<<(MM*NE/4 + 255)/256, 256, 0, stream>>>(x, xh, MM*NE);
  dim3 tg(NE/32, NE/32);
  for (int i=0;i<3;++i){
    transpose_w_k<<<tg, 256, 0, stream>>>(w1[i], wt1[i]);
    transpose_w_k<<<tg, 256, 0, stream>>>(w2[i], wt2[i]);
  }
  dim3 gg(MM/128, NE/128);
  gemm_mlp_k<true,  false><<<gg, 256, 0, stream>>>(xh, wt1[0], b1[0], H);
  gemm_mlp_k<false, false><<<gg, 256, 0, stream>>>(H,  wt2[0], b2[0], qh);
  gemm_mlp_k<true,  false><<<gg, 256, 0, stream>>>(xh, wt1[1], b1[1], H);
  gemm_mlp_k<false, false><<<gg, 256, 0, stream>>>(H,  wt2[1], b2[1], kh);
  gemm_mlp_k<true,  false><<<gg, 256, 0, stream>>>(xh, wt1[2], b1[2], H);
  gemm_mlp_k<false, true ><<<gg, 256, 0, stream>>>(H,  wt2[2], b2[2], vt);

  attn_qk_k<<<dim3(TT/64, NB), 256, 0, stream>>>(qh, kh, sb);
  attn_pv_k<<<dim3(TT/64, NE/64, NB), 256, 0, stream>>>(sb, vt, y);
  layernorm_k<<<MM/4, 256, 0, stream>>>(y, lnw, lnb, (float*)d_out);
}

// Round 2
// 447.039 us; speedup vs baseline: 1.1490x; 1.1490x over previous
//
#include <hip/hip_runtime.h>

typedef _Float16 f16;
typedef _Float16 half8 __attribute__((ext_vector_type(8)));
typedef float float4v __attribute__((ext_vector_type(4)));

#define NE 768
#define N3 2304
#define TT 4096
#define NB 4
#define MM (NB*TT)
#define SPAN 256
#define JW 320   // 5 key-tiles of 64 cover j in [qt*64-256, qt*64+64)

#define GLDS(g, l) __builtin_amdgcn_global_load_lds( \
    (const __attribute__((address_space(1))) void*)(g), \
    (__attribute__((address_space(3))) void*)(l), 16, 0, 0)

__device__ __forceinline__ float gelu_exact(float v){
  return 0.5f * v * (1.0f + erff(v * 0.70710678118654752440f));
}

// ---------- fp32 -> fp16 convert ----------
__global__ __launch_bounds__(256) void cvt_f16_k(const float* __restrict__ in,
                                                 f16* __restrict__ out, int n){
  int i = (blockIdx.x*256 + threadIdx.x)*4;
  if (i >= n) return;
  float4 v = *(const float4*)(in + i);
  struct alignas(8) H4 { f16 a,b,c,d; };
  H4 o; o.a=(f16)v.x; o.b=(f16)v.y; o.c=(f16)v.z; o.d=(f16)v.w;
  *(H4*)(out + i) = o;
}

// ---------- W[k][n] fp32 -> Wt[n][k] fp16 ----------
__global__ __launch_bounds__(256) void transpose_w_k(const float* __restrict__ W,
                                                     f16* __restrict__ Wt){
  __shared__ float tile[32][33];
  int tx = threadIdx.x & 31, ty = threadIdx.x >> 5;   // 32 x 8
  int bx = blockIdx.x * 32, by = blockIdx.y * 32;
  #pragma unroll
  for (int r=0;r<32;r+=8) tile[ty+r][tx] = W[(size_t)(by+ty+r)*NE + bx + tx];
  __syncthreads();
  #pragma unroll
  for (int r=0;r<32;r+=8) Wt[(size_t)(bx+ty+r)*NE + by + tx] = (f16)tile[tx][ty+r];
}

// ---------- pack 3 bias vectors into one [2304] ----------
__global__ void pack3_k(const float* __restrict__ a, const float* __restrict__ b,
                        const float* __restrict__ c, float* __restrict__ o){
  int i = blockIdx.x*256 + threadIdx.x;
  if (i < NE) o[i] = a[i];
  else if (i < 2*NE) o[i] = b[i-NE];
  else if (i < N3) o[i] = c[i-2*NE];
}

// ---------- m97-style GEMM core: 128x128 tile, BK=32, gload_lds(16B), swizzled ----------
// LDS[r][slot s] holds global k-chunk (s ^ ((r>>1)&3)) of 8 f16. Both-sides swizzle.
__device__ __forceinline__ void gemm_core(
    const f16* __restrict__ A, int lda,
    const f16* __restrict__ Bt,
    int brow, int bcol, f16* As, f16* Bs, float4v (&acc)[4][4])
{
  const int tid  = threadIdx.x;
  const int lane = tid & 63, wave = tid >> 6;
  const int l15 = lane & 15, lk = lane >> 4;
  const int wr = (wave >> 1)*64, wc = (wave & 1)*64;
  const int srow0 = wave*32 + (lane >> 2);     // staging row for t=0 (t=1: +16)
  const int sslot = lane & 3;
  const int fsw = (lk ^ ((l15 >> 1) & 3)) * 8; // fragment-read swizzled slot

  for (int k0 = 0; k0 < NE; k0 += 32){
    #pragma unroll
    for (int t=0; t<2; ++t){
      int r  = srow0 + t*16;
      int sw = (sslot ^ ((r >> 1) & 3)) * 8;   // swizzled global chunk
      GLDS(A  + (size_t)(brow + r)*lda + k0 + sw, As + (wave*32 + t*16)*32);
      GLDS(Bt + (size_t)(bcol + r)*NE  + k0 + sw, Bs + (wave*32 + t*16)*32);
    }
    __syncthreads();
    half8 af[4], bf[4];
    #pragma unroll
    for (int i=0;i<4;++i) af[i] = *(const half8*)&As[(wr + i*16 + l15)*32 + fsw];
    #pragma unroll
    for (int j=0;j<4;++j) bf[j] = *(const half8*)&Bs[(wc + j*16 + l15)*32 + fsw];
    #pragma unroll
    for (int i=0;i<4;++i)
      #pragma unroll
      for (int j=0;j<4;++j)
        acc[i][j] = __builtin_amdgcn_mfma_f32_16x16x32_f16(af[i], bf[j], acc[i][j], 0, 0, 0);
    __syncthreads();
  }
}

// ---------- layer-1: H_all[MM][2304] = gelu(xh @ wt1_all^T + b1_all) ----------
__global__ __launch_bounds__(256) void gemm_l1_k(
    const f16* __restrict__ A, const f16* __restrict__ Bt,
    const float* __restrict__ bias, f16* __restrict__ Out)
{
  __shared__ f16 smem[8192];
  float4v acc[4][4]{};
  const int brow = blockIdx.x*128, bcol = blockIdx.y*128;
  gemm_core(A, NE, Bt, brow, bcol, smem, smem + 4096, acc);

  const int lane = threadIdx.x & 63, wave = threadIdx.x >> 6;
  const int l15 = lane & 15, lk = lane >> 4;
  const int wr = (wave >> 1)*64, wc = (wave & 1)*64;
  #pragma unroll
  for (int j=0;j<4;++j){
    int col = bcol + wc + j*16 + l15;
    float bv = bias[col];
    #pragma unroll
    for (int i=0;i<4;++i){
      #pragma unroll
      for (int r=0;r<4;++r){
        int row = brow + wr + i*16 + lk*4 + r;
        Out[(size_t)row*N3 + col] = (f16)gelu_exact(acc[i][j][r] + bv);
      }
    }
  }
}

// ---------- layer-2 (z=0,1,2): q/k row-major, v transposed [NB][NE][TT] ----------
__global__ __launch_bounds__(256) void gemm_l2_k(
    const f16* __restrict__ H, const f16* __restrict__ wt2_all,
    const float* __restrict__ b2_all,
    f16* __restrict__ qh, f16* __restrict__ kh, f16* __restrict__ vt)
{
  __shared__ f16 smem[17408];   // staging (8192) U transpose buffer 128*136
  float4v acc[4][4]{};
  const int z = blockIdx.z;
  const int brow = blockIdx.x*128, bcol = blockIdx.y*128;
  gemm_core(H + z*NE, N3, wt2_all + (size_t)z*NE*NE, brow, bcol, smem, smem + 4096, acc);

  const float* bias = b2_all + z*NE;
  const int tid = threadIdx.x, lane = tid & 63, wave = tid >> 6;
  const int l15 = lane & 15, lk = lane >> 4;
  const int wr = (wave >> 1)*64, wc = (wave & 1)*64;

  if (z < 2){
    f16* Out = z ? kh : qh;
    #pragma unroll
    for (int j=0;j<4;++j){
      int col = bcol + wc + j*16 + l15;
      float bv = bias[col];
      #pragma unroll
      for (int i=0;i<4;++i){
        #pragma unroll
        for (int r=0;r<4;++r){
          int row = brow + wr + i*16 + lk*4 + r;
          Out[(size_t)row*NE + col] = (f16)(acc[i][j][r] + bv);
        }
      }
    }
  } else {
    __syncthreads();   // staging LDS dead, reuse as transpose buffer
    #pragma unroll
    for (int j=0;j<4;++j){
      int cl = wc + j*16 + l15;          // local col (d)
      float bv = bias[bcol + cl];
      #pragma unroll
      for (int i=0;i<4;++i){
        #pragma unroll
        for (int r=0;r<4;++r){
          int rl = wr + i*16 + lk*4 + r; // local row (t)
          smem[cl*136 + rl] = (f16)(acc[i][j][r] + bv);
        }
      }
    }
    __syncthreads();
    int b = brow / TT, t0 = brow % TT;   // 4096 % 128 == 0
    #pragma unroll
    for (int it=0; it<8; ++it){
      int idx = tid + it*256;            // 0..2047
      int c = idx >> 4, rr = (idx & 15)*8;
      half8 v = *(const half8*)&smem[c*136 + rr];
      *(half8*)(vt + (size_t)b*NE*TT + (size_t)(bcol + c)*TT + t0 + rr) = v;
    }
  }
}

// ---------- banded QK^T: S[row][c] = mask * (q_row . k_{jbase+c}) / SCALE ----------
__global__ __launch_bounds__(256) void attn_qk_k(
    const f16* __restrict__ Q, const f16* __restrict__ K, f16* __restrict__ S)
{
  __shared__ f16 Ks[JW*40];
  const int tid = threadIdx.x, lane = tid & 63, wave = tid >> 6;
  const int l15 = lane & 15, lk = lane >> 4;
  const int qt = blockIdx.x, b = blockIdx.y;
  const int rowbase = b*TT + qt*64;
  const int jbase = qt*64 - SPAN;
  const int qrow = rowbase + wave*16;

  float4v acc[20]{};

  for (int k0 = 0; k0 < NE; k0 += 32){
    #pragma unroll
    for (int it=0; it<5; ++it){
      int idx = tid + it*256;              // 0..1279
      int r = idx >> 2, c = (idx & 3)*8;   // j-row 0..319
      int j = jbase + r;
      half8 v{};
      if (j >= 0) v = *(const half8*)(K + (size_t)(b*TT + j)*NE + k0 + c);
      *(half8*)&Ks[r*40 + c] = v;
    }
    __syncthreads();
    half8 aq = *(const half8*)(Q + (size_t)(qrow + l15)*NE + k0 + lk*8);
    #pragma unroll
    for (int f=0; f<20; ++f){
      half8 bk = *(const half8*)&Ks[(f*16 + l15)*40 + lk*8];
      acc[f] = __builtin_amdgcn_mfma_f32_16x16x32_f16(aq, bk, acc[f], 0, 0, 0);
    }
    __syncthreads();
  }
  const float inv = 1.0f / 443.40500673763256f;  // 1/sqrt(768*256)
  #pragma unroll
  for (int f=0; f<20; ++f){
    int c = f*16 + l15;
    int jg = jbase + c;
    #pragma unroll
    for (int r=0;r<4;++r){
      int iloc = wave*16 + lk*4 + r;
      int d = (qt*64 + iloc) - jg;
      float v = (d >= 0 && d < SPAN) ? acc[f][r]*inv : 0.0f;
      S[(size_t)(rowbase + iloc)*JW + c] = (f16)v;
    }
  }
}

// ---------- PV: Y[row][d] = sum_j S[row][j] * V[j][d], V given transposed ----------
__global__ __launch_bounds__(256) void attn_pv_k(
    const f16* __restrict__ S, const f16* __restrict__ Vt, float* __restrict__ Y)
{
  __shared__ f16 Vs[64*328];
  const int tid = threadIdx.x, lane = tid & 63, wave = tid >> 6;
  const int l15 = lane & 15, lk = lane >> 4;
  const int qt = blockIdx.x, dc = blockIdx.y, b = blockIdx.z;
  const int d0 = dc*64;
  const int jbase = qt*64 - SPAN;
  const int rowbase = b*TT + qt*64;

  #pragma unroll
  for (int it=0; it<10; ++it){
    int idx = tid + it*256;                // 0..2559
    int dd = idx / 40;
    int c = (idx - dd*40)*8;               // j-offset 0..312
    int j = jbase + c;                     // chunk of 8 shares sign
    half8 v{};
    if (j >= 0) v = *(const half8*)(Vt + ((size_t)b*NE + d0 + dd)*TT + j);
    *(half8*)&Vs[dd*328 + c] = v;
  }
  __syncthreads();

  float4v acc[4]{};
  const f16* srow = S + (size_t)(rowbase + wave*16 + l15)*JW;
  #pragma unroll
  for (int kt = 0; kt < JW; kt += 32){
    half8 as = *(const half8*)(srow + kt + lk*8);
    #pragma unroll
    for (int nf=0; nf<4; ++nf){
      half8 bv = *(const half8*)&Vs[(nf*16 + l15)*328 + kt + lk*8];
      acc[nf] = __builtin_amdgcn_mfma_f32_16x16x32_f16(as, bv, acc[nf], 0, 0, 0);
    }
  }
  #pragma unroll
  for (int nf=0; nf<4; ++nf){
    #pragma unroll
    for (int r=0;r<4;++r){
      int row = rowbase + wave*16 + lk*4 + r;
      Y[(size_t)row*NE + d0 + nf*16 + l15] = acc[nf][r];
    }
  }
}

// ---------- LayerNorm over last dim (768), one wave per row ----------
__global__ __launch_bounds__(256) void layernorm_k(
    const float* __restrict__ Y, const float* __restrict__ g,
    const float* __restrict__ be, float* __restrict__ Out)
{
  int row  = blockIdx.x*4 + (threadIdx.x >> 6);
  int lane = threadIdx.x & 63;
  const float* y = Y + (size_t)row*NE;
  float v[12], s=0.f, s2=0.f;
  #pragma unroll
  for (int i=0;i<12;++i){ v[i] = y[lane + i*64]; s += v[i]; s2 += v[i]*v[i]; }
  #pragma unroll
  for (int m=32;m>=1;m>>=1){ s += __shfl_xor(s,m,64); s2 += __shfl_xor(s2,m,64); }
  float mu  = s*(1.f/NE);
  float var = s2*(1.f/NE) - mu*mu;
  float rs  = rsqrtf(var + 1e-5f);
  float* o = Out + (size_t)row*NE;
  #pragma unroll
  for (int i=0;i<12;++i){ int c = lane + i*64; o[c] = (v[i]-mu)*rs*g[c] + be[c]; }
}

extern "C" void kernel_launch(void* const* d_in, const int* in_sizes, int n_in,
                              void* d_out, int out_size, void* d_ws, size_t ws_size,
                              hipStream_t stream)
{
  (void)in_sizes; (void)n_in; (void)out_size; (void)ws_size;
  const float* x     = (const float*)d_in[0];
  const float* w1[3] = {(const float*)d_in[1], (const float*)d_in[5], (const float*)d_in[9]};
  const float* b1[3] = {(const float*)d_in[2], (const float*)d_in[6], (const float*)d_in[10]};
  const float* w2[3] = {(const float*)d_in[3], (const float*)d_in[7], (const float*)d_in[11]};
  const float* b2[3] = {(const float*)d_in[4], (const float*)d_in[8], (const float*)d_in[12]};
  const float* lnw = (const float*)d_in[13];
  const float* lnb = (const float*)d_in[14];

  char* ws = (char*)d_ws;
  size_t off = 0;
  auto alloc = [&](size_t bytes)->void* {
    void* p = ws + off; off += (bytes + 255) & ~size_t(255); return p;
  };
  f16* xh  = (f16*)alloc((size_t)MM*NE*2);   // 25.2 MB; reused as sb after layer-1
  f16* Ha  = (f16*)alloc((size_t)MM*N3*2);   // 75.5 MB; reused as y after layer-2
  f16* qh  = (f16*)alloc((size_t)MM*NE*2);
  f16* kh  = (f16*)alloc((size_t)MM*NE*2);
  f16* vt  = (f16*)alloc((size_t)MM*NE*2);   // [NB][NE][TT]
  f16* wt1 = (f16*)alloc((size_t)N3*NE*2);
  f16* wt2 = (f16*)alloc((size_t)N3*NE*2);
  float* b1a = (float*)alloc((size_t)N3*4);
  float* b2a = (float*)alloc((size_t)N3*4);
  f16*   sb  = xh;                            // banded scores [MM][320] (10.5 MB)
  float* y   = (float*)Ha;                    // [MM][768] f32 (50.3 MB)

  cvt_f16_k<<<(MM*NE/4 + 255)/256, 256, 0, stream>>>(x, xh, MM*NE);
  dim3 tg(NE/32, NE/32);
  for (int i=0;i<3;++i){
    transpose_w_k<<<tg, 256, 0, stream>>>(w1[i], wt1 + (size_t)i*NE*NE);
    transpose_w_k<<<tg, 256, 0, stream>>>(w2[i], wt2 + (size_t)i*NE*NE);
  }
  pack3_k<<<9, 256, 0, stream>>>(b1[0], b1[1], b1[2], b1a);
  pack3_k<<<9, 256, 0, stream>>>(b2[0], b2[1], b2[2], b2a);

  gemm_l1_k<<<dim3(MM/128, N3/128), 256, 0, stream>>>(xh, wt1, b1a, Ha);
  gemm_l2_k<<<dim3(MM/128, NE/128, 3), 256, 0, stream>>>(Ha, wt2, b2a, qh, kh, vt);

  attn_qk_k<<<dim3(TT/64, NB), 256, 0, stream>>>(qh, kh, sb);
  attn_pv_k<<<dim3(TT/64, NE/64, NB), 256, 0, stream>>>(sb, vt, y);
  layernorm_k<<<MM/4, 256, 0, stream>>>(y, lnw, lnb, (float*)d_out);
}

// Round 3
// 433.282 us; speedup vs baseline: 1.1855x; 1.0318x over previous
//
#include <hip/hip_runtime.h>

typedef _Float16 f16;
typedef _Float16 half8 __attribute__((ext_vector_type(8)));
typedef float float4v __attribute__((ext_vector_type(4)));

#define NE 768
#define N3 2304
#define TT 4096
#define NB 4
#define MM (NB*TT)
#define SPAN 256
#define JW 320

#define GLDS(g, l) __builtin_amdgcn_global_load_lds( \
    (const __attribute__((address_space(1))) void*)(g), \
    (__attribute__((address_space(3))) void*)(l), 16, 0, 0)

#define VMW(n) asm volatile("s_waitcnt vmcnt(" #n ")" ::: "memory")
#define LGKM0() asm volatile("s_waitcnt lgkmcnt(0)" ::: "memory")
#define SBAR() __builtin_amdgcn_s_barrier()
#define SCHED0() __builtin_amdgcn_sched_barrier(0)

__device__ __forceinline__ float gelu_exact(float v){
  return 0.5f * v * (1.0f + erff(v * 0.70710678118654752440f));
}

// ---------------- prep kernels ----------------
__global__ __launch_bounds__(256) void cvt_f16_k(const float* __restrict__ in,
                                                 f16* __restrict__ out, int n){
  int i = (blockIdx.x*256 + threadIdx.x)*4;
  if (i >= n) return;
  float4 v = *(const float4*)(in + i);
  struct alignas(8) H4 { f16 a,b,c,d; };
  H4 o; o.a=(f16)v.x; o.b=(f16)v.y; o.c=(f16)v.z; o.d=(f16)v.w;
  *(H4*)(out + i) = o;
}

__global__ __launch_bounds__(256) void transpose_w_k(const float* __restrict__ W,
                                                     f16* __restrict__ Wt){
  __shared__ float tile[32][33];
  int tx = threadIdx.x & 31, ty = threadIdx.x >> 5;
  int bx = blockIdx.x * 32, by = blockIdx.y * 32;
  #pragma unroll
  for (int r=0;r<32;r+=8) tile[ty+r][tx] = W[(size_t)(by+ty+r)*NE + bx + tx];
  __syncthreads();
  #pragma unroll
  for (int r=0;r<32;r+=8) Wt[(size_t)(bx+ty+r)*NE + by + tx] = (f16)tile[tx][ty+r];
}

__global__ void pack3_k(const float* __restrict__ a, const float* __restrict__ b,
                        const float* __restrict__ c, float* __restrict__ o){
  int i = blockIdx.x*256 + threadIdx.x;
  if (i < NE) o[i] = a[i];
  else if (i < 2*NE) o[i] = b[i-NE];
  else if (i < N3) o[i] = c[i-2*NE];
}

// ---------------- 256x256 8-phase GEMM core ----------------
// BM=BN=256, BK=64, 8 waves. LDS 128KB: 2 bufs x {A half0,A half1,B half0,B half1} x 8192 f16.
// Wave wm=w>>2, wn=w&3. m-frag i: row i*32+wm*16 (i<4 -> A half0, i>=4 -> half1).
// n-frag j: col j*64+wn*16 (j<2 -> B half0, else half1).
// LDS layout per half: [128 rows][8 slots of 8 f16], slot s holds global chunk s^(row&7).

__device__ __forceinline__ void read_a(half8 (&a)[4][2], const f16* h, int wm, int l15, int lk, int ax){
  #pragma unroll
  for (int i=0;i<4;++i){
    const f16* p = h + (i*32 + wm*16 + l15)*64;
    a[i][0] = *(const half8*)(p + ((lk*8)     ^ ax));
    a[i][1] = *(const half8*)(p + ((32+lk*8)  ^ ax));
  }
}
__device__ __forceinline__ void read_b(half8 (&b)[2][2], const f16* h, int wn, int l15, int lk, int ax){
  #pragma unroll
  for (int j=0;j<2;++j){
    const f16* p = h + (j*64 + wn*16 + l15)*64;
    b[j][0] = *(const half8*)(p + ((lk*8)     ^ ax));
    b[j][1] = *(const half8*)(p + ((32+lk*8)  ^ ax));
  }
}

template<int IB, int JB>
__device__ __forceinline__ void mfmaq(float4v (&acc)[8][4], half8 (&a)[4][2], half8 (&b)[2][2]){
  __builtin_amdgcn_s_setprio(1);
  #pragma unroll
  for (int kk=0;kk<2;++kk)
    #pragma unroll
    for (int i=0;i<4;++i)
      #pragma unroll
      for (int j=0;j<2;++j)
        acc[IB+i][JB+j] = __builtin_amdgcn_mfma_f32_16x16x32_f16(a[i][kk], b[j][kk], acc[IB+i][JB+j], 0, 0, 0);
  __builtin_amdgcn_s_setprio(0);
}

#define STG(srcbase, ld, k, dst) do{ \
  GLDS((srcbase) + (k),                    (dst) + wave*1024); \
  GLDS((srcbase) + (size_t)8*(ld) + (k),   (dst) + wave*1024 + 512); }while(0)

__device__ __forceinline__ void gemm256_core(
    const f16* __restrict__ A, int lda, const f16* __restrict__ Bt, int ldb,
    int brow, int bcol, f16* sh, float4v (&acc)[8][4])
{
  const int tid = threadIdx.x, lane = tid&63, wave = tid>>6;
  const int wm = wave>>2, wn = wave&3, l15 = lane&15, lk = lane>>4;
  const int ax = (l15&7)*8;
  half8 a[4][2], b0[2][2], b1[2][2];

  // per-thread staging source bases (row = wave*16 + lane>>3, swizzled slot)
  const int rr = wave*16 + (lane>>3);
  const int ss8 = ((lane&7) ^ (lane>>3))*8;
  const f16* As0 = A  + (size_t)(brow + rr)*lda + ss8;
  const f16* As1 = As0 + (size_t)128*lda;
  const f16* Bs0 = Bt + (size_t)(bcol + rr)*ldb + ss8;
  const f16* Bs1 = Bs0 + (size_t)128*ldb;

  const int T = NE/64;  // 12 K-tiles

  // prologue: stage tile 0 (order A0,B0,B1,A1) into buf0
  STG(As0, lda, 0, sh + 0);
  STG(Bs0, ldb, 0, sh + 16384);
  STG(Bs1, ldb, 0, sh + 16384 + 8192);
  STG(As1, lda, 0, sh + 8192);
  VMW(4); SBAR(); SCHED0();

  for (int t=0; t<T-1; ++t){
    const int cur = t&1, nxt = cur^1;
    f16* Ac0 = sh + cur*32768;         f16* Ac1 = Ac0 + 8192;
    f16* Bc0 = Ac0 + 16384;            f16* Bc1 = Bc0 + 8192;
    f16* An0 = sh + nxt*32768;         f16* An1 = An0 + 8192;
    f16* Bn0 = An0 + 16384;            f16* Bn1 = Bn0 + 8192;
    const int k1 = (t+1)*64;
    // p0: consume A0,B0; stage A0(t+1)
    read_a(a, Ac0, wm, l15, lk, ax);
    read_b(b0, Bc0, wn, l15, lk, ax);
    STG(As0, lda, k1, An0);
    mfmaq<0,0>(acc, a, b0);
    VMW(4); SBAR(); SCHED0();
    // p1: consume B1; stage B0(t+1)
    read_b(b1, Bc1, wn, l15, lk, ax);
    STG(Bs0, ldb, k1, Bn0);
    mfmaq<0,2>(acc, a, b1);
    VMW(4); SBAR(); SCHED0();
    // p2: consume A1; stage B1(t+1)
    read_a(a, Ac1, wm, l15, lk, ax);
    STG(Bs1, ldb, k1, Bn1);
    mfmaq<4,2>(acc, a, b1);
    SBAR(); SCHED0();
    // p3: stage A1(t+1)
    STG(As1, lda, k1, An1);
    mfmaq<4,0>(acc, a, b0);
    VMW(4); SBAR(); SCHED0();
  }
  { // last tile (no staging)
    const int cur = (T-1)&1;
    f16* Ac0 = sh + cur*32768;         f16* Ac1 = Ac0 + 8192;
    f16* Bc0 = Ac0 + 16384;            f16* Bc1 = Bc0 + 8192;
    read_a(a, Ac0, wm, l15, lk, ax);
    read_b(b0, Bc0, wn, l15, lk, ax);
    mfmaq<0,0>(acc, a, b0);
    VMW(2); SBAR(); SCHED0();
    read_b(b1, Bc1, wn, l15, lk, ax);
    mfmaq<0,2>(acc, a, b1);
    VMW(0); SBAR(); SCHED0();
    read_a(a, Ac1, wm, l15, lk, ax);
    mfmaq<4,2>(acc, a, b1);
    LGKM0(); SBAR(); SCHED0();   // drain reads before LDS reuse by epilogue
    mfmaq<4,0>(acc, a, b0);
  }
}

// ---------------- layer-1: H_all = gelu(xh @ wt1^T + b1) ----------------
__global__ __launch_bounds__(512, 2) void gemm8_l1_k(
    const f16* __restrict__ A, const f16* __restrict__ Bt,
    const float* __restrict__ bias, f16* __restrict__ Out)
{
  extern __shared__ __align__(16) f16 sh[];
  const int tid = threadIdx.x, lane = tid&63, wave = tid>>6;
  const int wm = wave>>2, wn = wave&3, l15 = lane&15, lk = lane>>4;
  int bid = blockIdx.y*64 + blockIdx.x;
  int L = (bid&7)*72 + (bid>>3);          // XCD-contiguous chunks (576%8==0)
  int brow = (L/9)*256, bcol = (L%9)*256;

  float4v acc[8][4]{};
  gemm256_core(A, NE, Bt, NE, brow, bcol, sh, acc);

  #pragma unroll
  for (int j=0;j<4;++j){
    int col = j*64 + wn*16 + l15;
    float bv = bias[bcol+col];
    #pragma unroll
    for (int i=0;i<8;++i){
      #pragma unroll
      for (int r=0;r<4;++r){
        int row = i*32 + wm*16 + lk*4 + r;
        sh[row*256 + (col ^ ((row&7)<<3))] = (f16)gelu_exact(acc[i][j][r] + bv);
      }
    }
  }
  SBAR();
  #pragma unroll
  for (int it=0;it<16;++it){
    int idx = tid + it*512;
    int row = idx>>5, cc = (idx&31)*8;
    half8 v = *(const half8*)(sh + row*256 + (cc ^ ((row&7)<<3)));
    *(half8*)(Out + (size_t)(brow+row)*N3 + bcol + cc) = v;
  }
}

// ---------------- layer-2 (z=0,1,2): q/k row-major, v transposed ----------------
__global__ __launch_bounds__(512, 2) void gemm8_l2_k(
    const f16* __restrict__ H, const f16* __restrict__ wt2_all,
    const float* __restrict__ b2_all,
    f16* __restrict__ qh, f16* __restrict__ kh, f16* __restrict__ vt)
{
  extern __shared__ __align__(16) f16 sh[];
  const int tid = threadIdx.x, lane = tid&63, wave = tid>>6;
  const int wm = wave>>2, wn = wave&3, l15 = lane&15, lk = lane>>4;
  const int z = blockIdx.z;
  int bid = blockIdx.y*64 + blockIdx.x;
  int L = (bid&7)*24 + (bid>>3);          // 192 blocks per z, 192%8==0
  int brow = (L/3)*256, bcol = (L%3)*256;

  float4v acc[8][4]{};
  gemm256_core(H + z*NE, N3, wt2_all + (size_t)z*NE*NE, NE, brow, bcol, sh, acc);

  const float* bias = b2_all + z*NE;
  if (z < 2){
    f16* Out = z ? kh : qh;
    #pragma unroll
    for (int j=0;j<4;++j){
      int col = j*64 + wn*16 + l15;
      float bv = bias[bcol+col];
      #pragma unroll
      for (int i=0;i<8;++i){
        #pragma unroll
        for (int r=0;r<4;++r){
          int row = i*32 + wm*16 + lk*4 + r;
          sh[row*256 + (col ^ ((row&7)<<3))] = (f16)(acc[i][j][r] + bv);
        }
      }
    }
    SBAR();
    #pragma unroll
    for (int it=0;it<16;++it){
      int idx = tid + it*512;
      int row = idx>>5, cc = (idx&31)*8;
      half8 v = *(const half8*)(sh + row*256 + (cc ^ ((row&7)<<3)));
      *(half8*)(Out + (size_t)(brow+row)*NE + bcol + cc) = v;
    }
  } else {
    // transposed store: vt[b][d][t]
    #pragma unroll
    for (int j=0;j<4;++j){
      int col = j*64 + wn*16 + l15;
      float bv = bias[bcol+col];
      #pragma unroll
      for (int i=0;i<8;++i){
        #pragma unroll
        for (int r=0;r<4;++r){
          int row = i*32 + wm*16 + lk*4 + r;
          sh[col*256 + (row ^ ((col&7)<<3))] = (f16)(acc[i][j][r] + bv);
        }
      }
    }
    SBAR();
    int b = brow / TT, t0 = brow % TT;   // 4096 % 256 == 0
    #pragma unroll
    for (int it=0;it<16;++it){
      int idx = tid + it*512;
      int col = idx>>5, rc = (idx&31)*8;
      half8 v = *(const half8*)(sh + col*256 + (rc ^ ((col&7)<<3)));
      *(half8*)(vt + (size_t)b*NE*TT + (size_t)(bcol+col)*TT + t0 + rc) = v;
    }
  }
}

// ---------------- banded QK^T ----------------
__global__ __launch_bounds__(256) void attn_qk_k(
    const f16* __restrict__ Q, const f16* __restrict__ K, f16* __restrict__ S)
{
  __shared__ f16 Ks[JW*40];
  const int tid = threadIdx.x, lane = tid & 63, wave = tid >> 6;
  const int l15 = lane & 15, lk = lane >> 4;
  const int qt = blockIdx.x, b = blockIdx.y;
  const int rowbase = b*TT + qt*64;
  const int jbase = qt*64 - SPAN;
  const int qrow = rowbase + wave*16;

  float4v acc[20]{};

  for (int k0 = 0; k0 < NE; k0 += 32){
    #pragma unroll
    for (int it=0; it<5; ++it){
      int idx = tid + it*256;
      int r = idx >> 2, c = (idx & 3)*8;
      int j = jbase + r;
      half8 v{};
      if (j >= 0) v = *(const half8*)(K + (size_t)(b*TT + j)*NE + k0 + c);
      *(half8*)&Ks[r*40 + c] = v;
    }
    __syncthreads();
    half8 aq = *(const half8*)(Q + (size_t)(qrow + l15)*NE + k0 + lk*8);
    #pragma unroll
    for (int f=0; f<20; ++f){
      half8 bk = *(const half8*)&Ks[(f*16 + l15)*40 + lk*8];
      acc[f] = __builtin_amdgcn_mfma_f32_16x16x32_f16(aq, bk, acc[f], 0, 0, 0);
    }
    __syncthreads();
  }
  const float inv = 1.0f / 443.40500673763256f;
  #pragma unroll
  for (int f=0; f<20; ++f){
    int c = f*16 + l15;
    int jg = jbase + c;
    #pragma unroll
    for (int r=0;r<4;++r){
      int iloc = wave*16 + lk*4 + r;
      int d = (qt*64 + iloc) - jg;
      float v = (d >= 0 && d < SPAN) ? acc[f][r]*inv : 0.0f;
      S[(size_t)(rowbase + iloc)*JW + c] = (f16)v;
    }
  }
}

// ---------------- PV ----------------
__global__ __launch_bounds__(256) void attn_pv_k(
    const f16* __restrict__ S, const f16* __restrict__ Vt, float* __restrict__ Y)
{
  __shared__ f16 Vs[64*328];
  const int tid = threadIdx.x, lane = tid & 63, wave = tid >> 6;
  const int l15 = lane & 15, lk = lane >> 4;
  const int qt = blockIdx.x, dc = blockIdx.y, b = blockIdx.z;
  const int d0 = dc*64;
  const int jbase = qt*64 - SPAN;
  const int rowbase = b*TT + qt*64;

  #pragma unroll
  for (int it=0; it<10; ++it){
    int idx = tid + it*256;
    int dd = idx / 40;
    int c = (idx - dd*40)*8;
    int j = jbase + c;
    half8 v{};
    if (j >= 0) v = *(const half8*)(Vt + ((size_t)b*NE + d0 + dd)*TT + j);
    *(half8*)&Vs[dd*328 + c] = v;
  }
  __syncthreads();

  float4v acc[4]{};
  const f16* srow = S + (size_t)(rowbase + wave*16 + l15)*JW;
  #pragma unroll
  for (int kt = 0; kt < JW; kt += 32){
    half8 as = *(const half8*)(srow + kt + lk*8);
    #pragma unroll
    for (int nf=0; nf<4; ++nf){
      half8 bv = *(const half8*)&Vs[(nf*16 + l15)*328 + kt + lk*8];
      acc[nf] = __builtin_amdgcn_mfma_f32_16x16x32_f16(as, bv, acc[nf], 0, 0, 0);
    }
  }
  #pragma unroll
  for (int nf=0; nf<4; ++nf){
    #pragma unroll
    for (int r=0;r<4;++r){
      int row = rowbase + wave*16 + lk*4 + r;
      Y[(size_t)row*NE + d0 + nf*16 + l15] = acc[nf][r];
    }
  }
}

// ---------------- LayerNorm ----------------
__global__ __launch_bounds__(256) void layernorm_k(
    const float* __restrict__ Y, const float* __restrict__ g,
    const float* __restrict__ be, float* __restrict__ Out)
{
  int row  = blockIdx.x*4 + (threadIdx.x >> 6);
  int lane = threadIdx.x & 63;
  const float* y = Y + (size_t)row*NE;
  float v[12], s=0.f, s2=0.f;
  #pragma unroll
  for (int i=0;i<12;++i){ v[i] = y[lane + i*64]; s += v[i]; s2 += v[i]*v[i]; }
  #pragma unroll
  for (int m=32;m>=1;m>>=1){ s += __shfl_xor(s,m,64); s2 += __shfl_xor(s2,m,64); }
  float mu  = s*(1.f/NE);
  float var = s2*(1.f/NE) - mu*mu;
  float rs  = rsqrtf(var + 1e-5f);
  float* o = Out + (size_t)row*NE;
  #pragma unroll
  for (int i=0;i<12;++i){ int c = lane + i*64; o[c] = (v[i]-mu)*rs*g[c] + be[c]; }
}

extern "C" void kernel_launch(void* const* d_in, const int* in_sizes, int n_in,
                              void* d_out, int out_size, void* d_ws, size_t ws_size,
                              hipStream_t stream)
{
  (void)in_sizes; (void)n_in; (void)out_size; (void)ws_size;
  const float* x     = (const float*)d_in[0];
  const float* w1[3] = {(const float*)d_in[1], (const float*)d_in[5], (const float*)d_in[9]};
  const float* b1[3] = {(const float*)d_in[2], (const float*)d_in[6], (const float*)d_in[10]};
  const float* w2[3] = {(const float*)d_in[3], (const float*)d_in[7], (const float*)d_in[11]};
  const float* b2[3] = {(const float*)d_in[4], (const float*)d_in[8], (const float*)d_in[12]};
  const float* lnw = (const float*)d_in[13];
  const float* lnb = (const float*)d_in[14];

  char* ws = (char*)d_ws;
  size_t off = 0;
  auto alloc = [&](size_t bytes)->void* {
    void* p = ws + off; off += (bytes + 255) & ~size_t(255); return p;
  };
  f16* xh  = (f16*)alloc((size_t)MM*NE*2);
  f16* Ha  = (f16*)alloc((size_t)MM*N3*2);
  f16* qh  = (f16*)alloc((size_t)MM*NE*2);
  f16* kh  = (f16*)alloc((size_t)MM*NE*2);
  f16* vt  = (f16*)alloc((size_t)MM*NE*2);
  f16* wt1 = (f16*)alloc((size_t)N3*NE*2);
  f16* wt2 = (f16*)alloc((size_t)N3*NE*2);
  float* b1a = (float*)alloc((size_t)N3*4);
  float* b2a = (float*)alloc((size_t)N3*4);
  f16*   sb  = xh;
  float* y   = (float*)Ha;

  static bool attr_done = false;
  hipFuncSetAttribute(reinterpret_cast<const void*>(&gemm8_l1_k),
                      hipFuncAttributeMaxDynamicSharedMemorySize, 131072);
  hipFuncSetAttribute(reinterpret_cast<const void*>(&gemm8_l2_k),
                      hipFuncAttributeMaxDynamicSharedMemorySize, 131072);
  (void)attr_done;

  cvt_f16_k<<<(MM*NE/4 + 255)/256, 256, 0, stream>>>(x, xh, MM*NE);
  dim3 tg(NE/32, NE/32);
  for (int i=0;i<3;++i){
    transpose_w_k<<<tg, 256, 0, stream>>>(w1[i], wt1 + (size_t)i*NE*NE);
    transpose_w_k<<<tg, 256, 0, stream>>>(w2[i], wt2 + (size_t)i*NE*NE);
  }
  pack3_k<<<9, 256, 0, stream>>>(b1[0], b1[1], b1[2], b1a);
  pack3_k<<<9, 256, 0, stream>>>(b2[0], b2[1], b2[2], b2a);

  gemm8_l1_k<<<dim3(64, 9), 512, 131072, stream>>>(xh, wt1, b1a, Ha);
  gemm8_l2_k<<<dim3(64, 3, 3), 512, 131072, stream>>>(Ha, wt2, b2a, qh, kh, vt);

  attn_qk_k<<<dim3(TT/64, NB), 256, 0, stream>>>(qh, kh, sb);
  attn_pv_k<<<dim3(TT/64, NE/64, NB), 256, 0, stream>>>(sb, vt, y);
  layernorm_k<<<MM/4, 256, 0, stream>>>(y, lnw, lnb, (float*)d_out);
}

// Round 4
// 427.443 us; speedup vs baseline: 1.2017x; 1.0137x over previous
//
#include <hip/hip_runtime.h>

typedef _Float16 f16;
typedef _Float16 half8 __attribute__((ext_vector_type(8)));
typedef float float4v __attribute__((ext_vector_type(4)));

#define NE 768
#define N3 2304
#define TT 4096
#define NB 4
#define MM (NB*TT)
#define SPAN 256
#define JW 320

#define GLDS(g, l) __builtin_amdgcn_global_load_lds( \
    (const __attribute__((address_space(1))) void*)(g), \
    (__attribute__((address_space(3))) void*)(l), 16, 0, 0)

__device__ __forceinline__ float gelu_exact(float v){
  return 0.5f * v * (1.0f + erff(v * 0.70710678118654752440f));
}

struct alignas(8) H4 { f16 a,b,c,d; };

// ---------------- prep kernels ----------------
__global__ __launch_bounds__(256) void cvt_f16_k(const float* __restrict__ in,
                                                 f16* __restrict__ out, int n){
  int i = (blockIdx.x*256 + threadIdx.x)*4;
  if (i >= n) return;
  float4 v = *(const float4*)(in + i);
  H4 o; o.a=(f16)v.x; o.b=(f16)v.y; o.c=(f16)v.z; o.d=(f16)v.w;
  *(H4*)(out + i) = o;
}

// 6 weight transposes in one dispatch: z=0..2 -> wt1, z=3..5 -> wt2
__global__ __launch_bounds__(256) void transpose_w6_k(
    const float* __restrict__ w0, const float* __restrict__ w1,
    const float* __restrict__ w2, const float* __restrict__ w3,
    const float* __restrict__ w4, const float* __restrict__ w5,
    f16* __restrict__ wt1, f16* __restrict__ wt2){
  __shared__ float tile[32][33];
  int z = blockIdx.z;
  const float* W = z==0?w0 : z==1?w1 : z==2?w2 : z==3?w3 : z==4?w4 : w5;
  f16* Wt = (z<3 ? wt1 + (size_t)z*NE*NE : wt2 + (size_t)(z-3)*NE*NE);
  int tx = threadIdx.x & 31, ty = threadIdx.x >> 5;
  int bx = blockIdx.x * 32, by = blockIdx.y * 32;
  #pragma unroll
  for (int r=0;r<32;r+=8) tile[ty+r][tx] = W[(size_t)(by+ty+r)*NE + bx + tx];
  __syncthreads();
  #pragma unroll
  for (int r=0;r<32;r+=8) Wt[(size_t)(bx+ty+r)*NE + by + tx] = (f16)tile[tx][ty+r];
}

// pack both bias triples in one dispatch
__global__ void packb_k(const float* __restrict__ a0, const float* __restrict__ a1,
                        const float* __restrict__ a2, const float* __restrict__ c0,
                        const float* __restrict__ c1, const float* __restrict__ c2,
                        float* __restrict__ o1, float* __restrict__ o2){
  int i = blockIdx.x*256 + threadIdx.x;   // 0..4607
  if (i < N3){
    const float* s = (i<NE) ? a0 : (i<2*NE ? a1 : a2);
    o1[i] = s[i % NE];
  } else if (i < 2*N3){
    int k = i - N3;
    const float* s = (k<NE) ? c0 : (k<2*NE ? c1 : c2);
    o2[k] = s[k % NE];
  }
}

// ---------------- m97-style GEMM core: 128x128, BK=32, 4 waves ----------------
// LDS[r][slot s] holds global k-chunk (s ^ ((r>>1)&3)) of 8 f16 (both-sides swizzle).
__device__ __forceinline__ void gemm_core(
    const f16* __restrict__ A, int lda,
    const f16* __restrict__ Bt,
    int brow, int bcol, f16* As, f16* Bs, float4v (&acc)[4][4])
{
  const int tid  = threadIdx.x;
  const int lane = tid & 63, wave = tid >> 6;
  const int l15 = lane & 15, lk = lane >> 4;
  const int wr = (wave >> 1)*64, wc = (wave & 1)*64;
  const int srow0 = wave*32 + (lane >> 2);     // staging row for t=0 (t=1: +16)
  const int sslot = lane & 3;
  const int fsw = (lk ^ ((l15 >> 1) & 3)) * 8; // fragment-read swizzled slot

  for (int k0 = 0; k0 < NE; k0 += 32){
    #pragma unroll
    for (int t=0; t<2; ++t){
      int r  = srow0 + t*16;
      int sw = (sslot ^ ((r >> 1) & 3)) * 8;   // swizzled global chunk
      GLDS(A  + (size_t)(brow + r)*lda + k0 + sw, As + (wave*32 + t*16)*32);
      GLDS(Bt + (size_t)(bcol + r)*NE  + k0 + sw, Bs + (wave*32 + t*16)*32);
    }
    __syncthreads();
    half8 af[4], bf[4];
    #pragma unroll
    for (int i=0;i<4;++i) af[i] = *(const half8*)&As[(wr + i*16 + l15)*32 + fsw];
    #pragma unroll
    for (int j=0;j<4;++j) bf[j] = *(const half8*)&Bs[(wc + j*16 + l15)*32 + fsw];
    #pragma unroll
    for (int i=0;i<4;++i)
      #pragma unroll
      for (int j=0;j<4;++j)
        acc[i][j] = __builtin_amdgcn_mfma_f32_16x16x32_f16(af[i], bf[j], acc[i][j], 0, 0, 0);
    __syncthreads();
  }
}

// ---------------- layer-1: H_all = gelu(xh @ wt1^T + b1) ----------------
__global__ __launch_bounds__(256) void gemm_l1_k(
    const f16* __restrict__ A, const f16* __restrict__ Bt,
    const float* __restrict__ bias, f16* __restrict__ Out)
{
  __shared__ f16 smem[16384];               // staging (8192) U epilogue [128][128^]
  float4v acc[4][4]{};
  const int bid = blockIdx.x;
  const int L = (bid & 7)*288 + (bid >> 3); // 2304 = 8*288, XCD-contiguous
  const int brow = (L/18)*128, bcol = (L%18)*128;
  gemm_core(A, NE, Bt, brow, bcol, smem, smem + 4096, acc);

  const int tid = threadIdx.x, lane = tid & 63, wave = tid >> 6;
  const int l15 = lane & 15, lk = lane >> 4;
  const int wr = (wave >> 1)*64, wc = (wave & 1)*64;
  #pragma unroll
  for (int j=0;j<4;++j){
    int col = wc + j*16 + l15;
    float bv = bias[bcol + col];
    #pragma unroll
    for (int i=0;i<4;++i){
      #pragma unroll
      for (int r=0;r<4;++r){
        int row = wr + i*16 + lk*4 + r;
        smem[row*128 + (col ^ ((row&7)<<3))] = (f16)gelu_exact(acc[i][j][r] + bv);
      }
    }
  }
  __syncthreads();
  #pragma unroll
  for (int it=0; it<8; ++it){
    int idx = tid + it*256;
    int row = idx >> 4, cc = (idx & 15)*8;
    half8 v = *(const half8*)&smem[row*128 + (cc ^ ((row&7)<<3))];
    *(half8*)(Out + (size_t)(brow + row)*N3 + bcol + cc) = v;
  }
}

// ---------------- layer-2 (z=0,1,2): q/k row-major, v transposed ----------------
__global__ __launch_bounds__(256) void gemm_l2_k(
    const f16* __restrict__ H, const f16* __restrict__ wt2_all,
    const float* __restrict__ b2_all,
    f16* __restrict__ qh, f16* __restrict__ kh, f16* __restrict__ vt)
{
  __shared__ f16 smem[16384];
  float4v acc[4][4]{};
  const int z = blockIdx.z;
  const int bid = blockIdx.x;
  const int L = (bid & 7)*96 + (bid >> 3);  // 768 = 8*96 per z
  const int brow = (L/6)*128, bcol = (L%6)*128;
  gemm_core(H + z*NE, N3, wt2_all + (size_t)z*NE*NE, brow, bcol, smem, smem + 4096, acc);

  const float* bias = b2_all + z*NE;
  const int tid = threadIdx.x, lane = tid & 63, wave = tid >> 6;
  const int l15 = lane & 15, lk = lane >> 4;
  const int wr = (wave >> 1)*64, wc = (wave & 1)*64;

  if (z < 2){
    f16* Out = z ? kh : qh;
    #pragma unroll
    for (int j=0;j<4;++j){
      int col = wc + j*16 + l15;
      float bv = bias[bcol + col];
      #pragma unroll
      for (int i=0;i<4;++i){
        #pragma unroll
        for (int r=0;r<4;++r){
          int row = wr + i*16 + lk*4 + r;
          smem[row*128 + (col ^ ((row&7)<<3))] = (f16)(acc[i][j][r] + bv);
        }
      }
    }
    __syncthreads();
    #pragma unroll
    for (int it=0; it<8; ++it){
      int idx = tid + it*256;
      int row = idx >> 4, cc = (idx & 15)*8;
      half8 v = *(const half8*)&smem[row*128 + (cc ^ ((row&7)<<3))];
      *(half8*)(Out + (size_t)(brow + row)*NE + bcol + cc) = v;
    }
  } else {
    // transposed epilogue: smem[col][row^swz], 4-row packs stay contiguous
    #pragma unroll
    for (int j=0;j<4;++j){
      int cl = wc + j*16 + l15;
      float bv = bias[bcol + cl];
      #pragma unroll
      for (int i=0;i<4;++i){
        int r0 = wr + i*16 + lk*4;
        H4 p; p.a = (f16)(acc[i][j][0] + bv); p.b = (f16)(acc[i][j][1] + bv);
              p.c = (f16)(acc[i][j][2] + bv); p.d = (f16)(acc[i][j][3] + bv);
        *(H4*)&smem[cl*128 + (r0 ^ ((cl&7)<<3))] = p;
      }
    }
    __syncthreads();
    int b = brow / TT, t0 = brow % TT;    // 4096 % 128 == 0
    #pragma unroll
    for (int it=0; it<8; ++it){
      int idx = tid + it*256;
      int col = idx >> 4, rc = (idx & 15)*8;
      half8 v = *(const half8*)&smem[col*128 + (rc ^ ((col&7)<<3))];
      *(half8*)(vt + (size_t)b*NE*TT + (size_t)(bcol + col)*TT + t0 + rc) = v;
    }
  }
}

// ---------------- banded QK^T ----------------
__global__ __launch_bounds__(256) void attn_qk_k(
    const f16* __restrict__ Q, const f16* __restrict__ K, f16* __restrict__ S)
{
  __shared__ f16 Ks[JW*40];
  const int tid = threadIdx.x, lane = tid & 63, wave = tid >> 6;
  const int l15 = lane & 15, lk = lane >> 4;
  const int qt = blockIdx.x, b = blockIdx.y;
  const int rowbase = b*TT + qt*64;
  const int jbase = qt*64 - SPAN;
  const int qrow = rowbase + wave*16;

  float4v acc[20]{};

  for (int k0 = 0; k0 < NE; k0 += 32){
    #pragma unroll
    for (int it=0; it<5; ++it){
      int idx = tid + it*256;
      int r = idx >> 2, c = (idx & 3)*8;
      int j = jbase + r;
      half8 v{};
      if (j >= 0) v = *(const half8*)(K + (size_t)(b*TT + j)*NE + k0 + c);
      *(half8*)&Ks[r*40 + c] = v;
    }
    __syncthreads();
    half8 aq = *(const half8*)(Q + (size_t)(qrow + l15)*NE + k0 + lk*8);
    #pragma unroll
    for (int f=0; f<20; ++f){
      half8 bk = *(const half8*)&Ks[(f*16 + l15)*40 + lk*8];
      acc[f] = __builtin_amdgcn_mfma_f32_16x16x32_f16(aq, bk, acc[f], 0, 0, 0);
    }
    __syncthreads();
  }
  const float inv = 1.0f / 443.40500673763256f;
  #pragma unroll
  for (int f=0; f<20; ++f){
    int c = f*16 + l15;
    int jg = jbase + c;
    #pragma unroll
    for (int r=0;r<4;++r){
      int iloc = wave*16 + lk*4 + r;
      int d = (qt*64 + iloc) - jg;
      float v = (d >= 0 && d < SPAN) ? acc[f][r]*inv : 0.0f;
      S[(size_t)(rowbase + iloc)*JW + c] = (f16)v;
    }
  }
}

// ---------------- PV ----------------
__global__ __launch_bounds__(256) void attn_pv_k(
    const f16* __restrict__ S, const f16* __restrict__ Vt, float* __restrict__ Y)
{
  __shared__ f16 Vs[64*328];
  const int tid = threadIdx.x, lane = tid & 63, wave = tid >> 6;
  const int l15 = lane & 15, lk = lane >> 4;
  const int qt = blockIdx.x, dc = blockIdx.y, b = blockIdx.z;
  const int d0 = dc*64;
  const int jbase = qt*64 - SPAN;
  const int rowbase = b*TT + qt*64;

  #pragma unroll
  for (int it=0; it<10; ++it){
    int idx = tid + it*256;
    int dd = idx / 40;
    int c = (idx - dd*40)*8;
    int j = jbase + c;
    half8 v{};
    if (j >= 0) v = *(const half8*)(Vt + ((size_t)b*NE + d0 + dd)*TT + j);
    *(half8*)&Vs[dd*328 + c] = v;
  }
  __syncthreads();

  float4v acc[4]{};
  const f16* srow = S + (size_t)(rowbase + wave*16 + l15)*JW;
  #pragma unroll
  for (int kt = 0; kt < JW; kt += 32){
    half8 as = *(const half8*)(srow + kt + lk*8);
    #pragma unroll
    for (int nf=0; nf<4; ++nf){
      half8 bv = *(const half8*)&Vs[(nf*16 + l15)*328 + kt + lk*8];
      acc[nf] = __builtin_amdgcn_mfma_f32_16x16x32_f16(as, bv, acc[nf], 0, 0, 0);
    }
  }
  #pragma unroll
  for (int nf=0; nf<4; ++nf){
    #pragma unroll
    for (int r=0;r<4;++r){
      int row = rowbase + wave*16 + lk*4 + r;
      Y[(size_t)row*NE + d0 + nf*16 + l15] = acc[nf][r];
    }
  }
}

// ---------------- LayerNorm ----------------
__global__ __launch_bounds__(256) void layernorm_k(
    const float* __restrict__ Y, const float* __restrict__ g,
    const float* __restrict__ be, float* __restrict__ Out)
{
  int row  = blockIdx.x*4 + (threadIdx.x >> 6);
  int lane = threadIdx.x & 63;
  const float* y = Y + (size_t)row*NE;
  float v[12], s=0.f, s2=0.f;
  #pragma unroll
  for (int i=0;i<12;++i){ v[i] = y[lane + i*64]; s += v[i]; s2 += v[i]*v[i]; }
  #pragma unroll
  for (int m=32;m>=1;m>>=1){ s += __shfl_xor(s,m,64); s2 += __shfl_xor(s2,m,64); }
  float mu  = s*(1.f/NE);
  float var = s2*(1.f/NE) - mu*mu;
  float rs  = rsqrtf(var + 1e-5f);
  float* o = Out + (size_t)row*NE;
  #pragma unroll
  for (int i=0;i<12;++i){ int c = lane + i*64; o[c] = (v[i]-mu)*rs*g[c] + be[c]; }
}

extern "C" void kernel_launch(void* const* d_in, const int* in_sizes, int n_in,
                              void* d_out, int out_size, void* d_ws, size_t ws_size,
                              hipStream_t stream)
{
  (void)in_sizes; (void)n_in; (void)out_size; (void)ws_size;
  const float* x     = (const float*)d_in[0];
  const float* w1[3] = {(const float*)d_in[1], (const float*)d_in[5], (const float*)d_in[9]};
  const float* b1[3] = {(const float*)d_in[2], (const float*)d_in[6], (const float*)d_in[10]};
  const float* w2[3] = {(const float*)d_in[3], (const float*)d_in[7], (const float*)d_in[11]};
  const float* b2[3] = {(const float*)d_in[4], (const float*)d_in[8], (const float*)d_in[12]};
  const float* lnw = (const float*)d_in[13];
  const float* lnb = (const float*)d_in[14];

  char* ws = (char*)d_ws;
  size_t off = 0;
  auto alloc = [&](size_t bytes)->void* {
    void* p = ws + off; off += (bytes + 255) & ~size_t(255); return p;
  };
  f16* xh  = (f16*)alloc((size_t)MM*NE*2);   // reused as sb after layer-1
  f16* Ha  = (f16*)alloc((size_t)MM*N3*2);   // reused as y after layer-2
  f16* qh  = (f16*)alloc((size_t)MM*NE*2);
  f16* kh  = (f16*)alloc((size_t)MM*NE*2);
  f16* vt  = (f16*)alloc((size_t)MM*NE*2);   // [NB][NE][TT]
  f16* wt1 = (f16*)alloc((size_t)N3*NE*2);
  f16* wt2 = (f16*)alloc((size_t)N3*NE*2);
  float* b1a = (float*)alloc((size_t)N3*4);
  float* b2a = (float*)alloc((size_t)N3*4);
  f16*   sb  = xh;
  float* y   = (float*)Ha;

  cvt_f16_k<<<(MM*NE/4 + 255)/256, 256, 0, stream>>>(x, xh, MM*NE);
  transpose_w6_k<<<dim3(NE/32, NE/32, 6), 256, 0, stream>>>(
      w1[0], w1[1], w1[2], w2[0], w2[1], w2[2], wt1, wt2);
  packb_k<<<18, 256, 0, stream>>>(b1[0], b1[1], b1[2], b2[0], b2[1], b2[2], b1a, b2a);

  gemm_l1_k<<<dim3(MM/128 * N3/128), 256, 0, stream>>>(xh, wt1, b1a, Ha);
  gemm_l2_k<<<dim3(MM/128 * NE/128, 1, 3), 256, 0, stream>>>(Ha, wt2, b2a, qh, kh, vt);

  attn_qk_k<<<dim3(TT/64, NB), 256, 0, stream>>>(qh, kh, sb);
  attn_pv_k<<<dim3(TT/64, NE/64, NB), 256, 0, stream>>>(sb, vt, y);
  layernorm_k<<<MM/4, 256, 0, stream>>>(y, lnw, lnb, (float*)d_out);
}

// Round 5
// 408.330 us; speedup vs baseline: 1.2579x; 1.0468x over previous
//
#include <hip/hip_runtime.h>

typedef _Float16 f16;
typedef _Float16 half8 __attribute__((ext_vector_type(8)));
typedef float float4v __attribute__((ext_vector_type(4)));

#define NE 768
#define N3 2304
#define TT 4096
#define NB 4
#define MM (NB*TT)
#define SPAN 256
#define JW 320

#define GLDS(g, l) __builtin_amdgcn_global_load_lds( \
    (const __attribute__((address_space(1))) void*)(g), \
    (__attribute__((address_space(3))) void*)(l), 16, 0, 0)

#define VMW(n) asm volatile("s_waitcnt vmcnt(" #n ")" ::: "memory")
#define SBAR() __builtin_amdgcn_s_barrier()
#define SCHED0() __builtin_amdgcn_sched_barrier(0)

__device__ __forceinline__ float gelu_exact(float v){
  return 0.5f * v * (1.0f + erff(v * 0.70710678118654752440f));
}

struct alignas(8) H4 { f16 a,b,c,d; };

// ---------------- prep kernels ----------------
__global__ __launch_bounds__(256) void cvt_f16_k(const float* __restrict__ in,
                                                 f16* __restrict__ out, int n){
  int i = (blockIdx.x*256 + threadIdx.x)*4;
  if (i >= n) return;
  float4 v = *(const float4*)(in + i);
  H4 o; o.a=(f16)v.x; o.b=(f16)v.y; o.c=(f16)v.z; o.d=(f16)v.w;
  *(H4*)(out + i) = o;
}

__global__ __launch_bounds__(256) void transpose_w6_k(
    const float* __restrict__ w0, const float* __restrict__ w1,
    const float* __restrict__ w2, const float* __restrict__ w3,
    const float* __restrict__ w4, const float* __restrict__ w5,
    f16* __restrict__ wt1, f16* __restrict__ wt2){
  __shared__ float tile[32][33];
  int z = blockIdx.z;
  const float* W = z==0?w0 : z==1?w1 : z==2?w2 : z==3?w3 : z==4?w4 : w5;
  f16* Wt = (z<3 ? wt1 + (size_t)z*NE*NE : wt2 + (size_t)(z-3)*NE*NE);
  int tx = threadIdx.x & 31, ty = threadIdx.x >> 5;
  int bx = blockIdx.x * 32, by = blockIdx.y * 32;
  #pragma unroll
  for (int r=0;r<32;r+=8) tile[ty+r][tx] = W[(size_t)(by+ty+r)*NE + bx + tx];
  __syncthreads();
  #pragma unroll
  for (int r=0;r<32;r+=8) Wt[(size_t)(bx+ty+r)*NE + by + tx] = (f16)tile[tx][ty+r];
}

__global__ void packb_k(const float* __restrict__ a0, const float* __restrict__ a1,
                        const float* __restrict__ a2, const float* __restrict__ c0,
                        const float* __restrict__ c1, const float* __restrict__ c2,
                        float* __restrict__ o1, float* __restrict__ o2){
  int i = blockIdx.x*256 + threadIdx.x;
  if (i < N3){
    const float* s = (i<NE) ? a0 : (i<2*NE ? a1 : a2);
    o1[i] = s[i % NE];
  } else if (i < 2*N3){
    int k = i - N3;
    const float* s = (k<NE) ? c0 : (k<2*NE ? c1 : c2);
    o2[k] = s[k % NE];
  }
}

// ---------------- 128x128 GEMM core, BK=64, double-buffered, counted vmcnt ----------------
// LDS: 2 bufs x [A 8192 | B 8192] f16 (64KB). Tile layout: [128 rows][8 slots of 8 f16],
// slot s of row r holds global k-chunk (s ^ (r&7)).  gload_lds dest is linear (wave-uniform
// base + lane*16B); the swizzle is applied on the GLOBAL source and on fragment reads.
__device__ __forceinline__ void gemm_core(
    const f16* __restrict__ A, int lda,
    const f16* __restrict__ Bt, int ldb,
    int brow, int bcol, f16* sh, float4v (&acc)[4][4])
{
  const int tid = threadIdx.x, lane = tid & 63, wave = tid >> 6;
  const int l15 = lane & 15, lk = lane >> 4;
  const int wr = (wave >> 1)*64, wc = (wave & 1)*64;

  const int srow   = wave*8 + (lane >> 3);           // staging source row (sweep adds 32)
  const int schunk = ((lane & 7) ^ (lane >> 3))*8;   // pre-swizzled global chunk
  const f16* Asrc = A  + (size_t)(brow + srow)*lda + schunk;
  const f16* Bsrc = Bt + (size_t)(bcol + srow)*ldb + schunk;
  const int wdst = wave*512;                          // wave-uniform LDS dst base (elems)

  const int rsw0 = (lk ^ (l15 & 7))*8;                // read slot, k-subtile 0
  const int rsw1 = ((4 + lk) ^ (l15 & 7))*8;          // read slot, k-subtile 1

#define STAGE(buf, k0) do{ \
    f16* _a = sh + (buf)*16384 + wdst; \
    f16* _b = _a + 8192; \
    const f16* _as = Asrc + (k0); \
    const f16* _bs = Bsrc + (k0); \
    _Pragma("unroll") \
    for (int _t = 0; _t < 4; ++_t){ \
      GLDS(_as + (size_t)(_t*32)*lda, _a + _t*2048); \
      GLDS(_bs + (size_t)(_t*32)*ldb, _b + _t*2048); \
    } }while(0)

  STAGE(0, 0);
  #pragma unroll
  for (int t = 0; t < 12; ++t){
    const f16* Ac = sh + (t & 1)*16384;
    const f16* Bc = Ac + 8192;
    if (t < 11) STAGE((t+1) & 1, (t+1)*64);
    if (t < 11) { VMW(8); } else { VMW(0); }
    SBAR(); SCHED0();
    half8 af0[4], af1[4], bf0[4], bf1[4];
    #pragma unroll
    for (int i=0;i<4;++i){
      const f16* pa = Ac + (wr + i*16 + l15)*64;
      af0[i] = *(const half8*)(pa + rsw0);
      af1[i] = *(const half8*)(pa + rsw1);
      const f16* pb = Bc + (wc + i*16 + l15)*64;
      bf0[i] = *(const half8*)(pb + rsw0);
      bf1[i] = *(const half8*)(pb + rsw1);
    }
    #pragma unroll
    for (int i=0;i<4;++i)
      #pragma unroll
      for (int j=0;j<4;++j)
        acc[i][j] = __builtin_amdgcn_mfma_f32_16x16x32_f16(af0[i], bf0[j], acc[i][j], 0, 0, 0);
    #pragma unroll
    for (int i=0;i<4;++i)
      #pragma unroll
      for (int j=0;j<4;++j)
        acc[i][j] = __builtin_amdgcn_mfma_f32_16x16x32_f16(af1[i], bf1[j], acc[i][j], 0, 0, 0);
    SCHED0(); SBAR();
  }
#undef STAGE
}

// ---------------- layer-1: H_all = gelu(xh @ wt1^T + b1) ----------------
__global__ __launch_bounds__(256) void gemm_l1_k(
    const f16* __restrict__ A, const f16* __restrict__ Bt,
    const float* __restrict__ bias, f16* __restrict__ Out)
{
  __shared__ f16 smem[32768];               // staging 2x16384 U epilogue [128][128^]
  float4v acc[4][4]{};
  const int bid = blockIdx.x;
  const int L = (bid & 7)*288 + (bid >> 3); // 2304 = 8*288, XCD-contiguous
  const int brow = (L/18)*128, bcol = (L%18)*128;
  gemm_core(A, NE, Bt, NE, brow, bcol, smem, acc);

  const int tid = threadIdx.x, lane = tid & 63, wave = tid >> 6;
  const int l15 = lane & 15, lk = lane >> 4;
  const int wr = (wave >> 1)*64, wc = (wave & 1)*64;
  #pragma unroll
  for (int j=0;j<4;++j){
    int col = wc + j*16 + l15;
    float bv = bias[bcol + col];
    #pragma unroll
    for (int i=0;i<4;++i){
      #pragma unroll
      for (int r=0;r<4;++r){
        int row = wr + i*16 + lk*4 + r;
        smem[row*128 + (col ^ ((row&7)<<3))] = (f16)gelu_exact(acc[i][j][r] + bv);
      }
    }
  }
  __syncthreads();
  #pragma unroll
  for (int it=0; it<8; ++it){
    int idx = tid + it*256;
    int row = idx >> 4, cc = (idx & 15)*8;
    half8 v = *(const half8*)&smem[row*128 + (cc ^ ((row&7)<<3))];
    *(half8*)(Out + (size_t)(brow + row)*N3 + bcol + cc) = v;
  }
}

// ---------------- layer-2 (z=0,1,2): q/k row-major, v transposed ----------------
__global__ __launch_bounds__(256) void gemm_l2_k(
    const f16* __restrict__ H, const f16* __restrict__ wt2_all,
    const float* __restrict__ b2_all,
    f16* __restrict__ qh, f16* __restrict__ kh, f16* __restrict__ vt)
{
  __shared__ f16 smem[32768];
  float4v acc[4][4]{};
  const int z = blockIdx.z;
  const int bid = blockIdx.x;
  const int L = (bid & 7)*96 + (bid >> 3);  // 768 = 8*96 per z
  const int brow = (L/6)*128, bcol = (L%6)*128;
  gemm_core(H + z*NE, N3, wt2_all + (size_t)z*NE*NE, NE, brow, bcol, smem, acc);

  const float* bias = b2_all + z*NE;
  const int tid = threadIdx.x, lane = tid & 63, wave = tid >> 6;
  const int l15 = lane & 15, lk = lane >> 4;
  const int wr = (wave >> 1)*64, wc = (wave & 1)*64;

  if (z < 2){
    f16* Out = z ? kh : qh;
    #pragma unroll
    for (int j=0;j<4;++j){
      int col = wc + j*16 + l15;
      float bv = bias[bcol + col];
      #pragma unroll
      for (int i=0;i<4;++i){
        #pragma unroll
        for (int r=0;r<4;++r){
          int row = wr + i*16 + lk*4 + r;
          smem[row*128 + (col ^ ((row&7)<<3))] = (f16)(acc[i][j][r] + bv);
        }
      }
    }
    __syncthreads();
    #pragma unroll
    for (int it=0; it<8; ++it){
      int idx = tid + it*256;
      int row = idx >> 4, cc = (idx & 15)*8;
      half8 v = *(const half8*)&smem[row*128 + (cc ^ ((row&7)<<3))];
      *(half8*)(Out + (size_t)(brow + row)*NE + bcol + cc) = v;
    }
  } else {
    // transposed epilogue: smem[col][row^swz], 4-row packs stay contiguous
    #pragma unroll
    for (int j=0;j<4;++j){
      int cl = wc + j*16 + l15;
      float bv = bias[bcol + cl];
      #pragma unroll
      for (int i=0;i<4;++i){
        int r0 = wr + i*16 + lk*4;
        H4 p; p.a = (f16)(acc[i][j][0] + bv); p.b = (f16)(acc[i][j][1] + bv);
              p.c = (f16)(acc[i][j][2] + bv); p.d = (f16)(acc[i][j][3] + bv);
        *(H4*)&smem[cl*128 + (r0 ^ ((cl&7)<<3))] = p;
      }
    }
    __syncthreads();
    int b = brow / TT, t0 = brow % TT;    // 4096 % 128 == 0
    #pragma unroll
    for (int it=0; it<8; ++it){
      int idx = tid + it*256;
      int col = idx >> 4, rc = (idx & 15)*8;
      half8 v = *(const half8*)&smem[col*128 + (rc ^ ((col&7)<<3))];
      *(half8*)(vt + (size_t)b*NE*TT + (size_t)(bcol + col)*TT + t0 + rc) = v;
    }
  }
}

// ---------------- banded QK^T ----------------
__global__ __launch_bounds__(256) void attn_qk_k(
    const f16* __restrict__ Q, const f16* __restrict__ K, f16* __restrict__ S)
{
  __shared__ f16 Ks[JW*40];
  const int tid = threadIdx.x, lane = tid & 63, wave = tid >> 6;
  const int l15 = lane & 15, lk = lane >> 4;
  const int qt = blockIdx.x, b = blockIdx.y;
  const int rowbase = b*TT + qt*64;
  const int jbase = qt*64 - SPAN;
  const int qrow = rowbase + wave*16;

  float4v acc[20]{};

  for (int k0 = 0; k0 < NE; k0 += 32){
    #pragma unroll
    for (int it=0; it<5; ++it){
      int idx = tid + it*256;
      int r = idx >> 2, c = (idx & 3)*8;
      int j = jbase + r;
      half8 v{};
      if (j >= 0) v = *(const half8*)(K + (size_t)(b*TT + j)*NE + k0 + c);
      *(half8*)&Ks[r*40 + c] = v;
    }
    __syncthreads();
    half8 aq = *(const half8*)(Q + (size_t)(qrow + l15)*NE + k0 + lk*8);
    #pragma unroll
    for (int f=0; f<20; ++f){
      half8 bk = *(const half8*)&Ks[(f*16 + l15)*40 + lk*8];
      acc[f] = __builtin_amdgcn_mfma_f32_16x16x32_f16(aq, bk, acc[f], 0, 0, 0);
    }
    __syncthreads();
  }
  const float inv = 1.0f / 443.40500673763256f;
  #pragma unroll
  for (int f=0; f<20; ++f){
    int c = f*16 + l15;
    int jg = jbase + c;
    #pragma unroll
    for (int r=0;r<4;++r){
      int iloc = wave*16 + lk*4 + r;
      int d = (qt*64 + iloc) - jg;
      float v = (d >= 0 && d < SPAN) ? acc[f][r]*inv : 0.0f;
      S[(size_t)(rowbase + iloc)*JW + c] = (f16)v;
    }
  }
}

// ---------------- PV ----------------
__global__ __launch_bounds__(256) void attn_pv_k(
    const f16* __restrict__ S, const f16* __restrict__ Vt, float* __restrict__ Y)
{
  __shared__ f16 Vs[64*328];
  const int tid = threadIdx.x, lane = tid & 63, wave = tid >> 6;
  const int l15 = lane & 15, lk = lane >> 4;
  const int qt = blockIdx.x, dc = blockIdx.y, b = blockIdx.z;
  const int d0 = dc*64;
  const int jbase = qt*64 - SPAN;
  const int rowbase = b*TT + qt*64;

  #pragma unroll
  for (int it=0; it<10; ++it){
    int idx = tid + it*256;
    int dd = idx / 40;
    int c = (idx - dd*40)*8;
    int j = jbase + c;
    half8 v{};
    if (j >= 0) v = *(const half8*)(Vt + ((size_t)b*NE + d0 + dd)*TT + j);
    *(half8*)&Vs[dd*328 + c] = v;
  }
  __syncthreads();

  float4v acc[4]{};
  const f16* srow = S + (size_t)(rowbase + wave*16 + l15)*JW;
  #pragma unroll
  for (int kt = 0; kt < JW; kt += 32){
    half8 as = *(const half8*)(srow + kt + lk*8);
    #pragma unroll
    for (int nf=0; nf<4; ++nf){
      half8 bv = *(const half8*)&Vs[(nf*16 + l15)*328 + kt + lk*8];
      acc[nf] = __builtin_amdgcn_mfma_f32_16x16x32_f16(as, bv, acc[nf], 0, 0, 0);
    }
  }
  #pragma unroll
  for (int nf=0; nf<4; ++nf){
    #pragma unroll
    for (int r=0;r<4;++r){
      int row = rowbase + wave*16 + lk*4 + r;
      Y[(size_t)row*NE + d0 + nf*16 + l15] = acc[nf][r];
    }
  }
}

// ---------------- LayerNorm ----------------
__global__ __launch_bounds__(256) void layernorm_k(
    const float* __restrict__ Y, const float* __restrict__ g,
    const float* __restrict__ be, float* __restrict__ Out)
{
  int row  = blockIdx.x*4 + (threadIdx.x >> 6);
  int lane = threadIdx.x & 63;
  const float* y = Y + (size_t)row*NE;
  float v[12], s=0.f, s2=0.f;
  #pragma unroll
  for (int i=0;i<12;++i){ v[i] = y[lane + i*64]; s += v[i]; s2 += v[i]*v[i]; }
  #pragma unroll
  for (int m=32;m>=1;m>>=1){ s += __shfl_xor(s,m,64); s2 += __shfl_xor(s2,m,64); }
  float mu  = s*(1.f/NE);
  float var = s2*(1.f/NE) - mu*mu;
  float rs  = rsqrtf(var + 1e-5f);
  float* o = Out + (size_t)row*NE;
  #pragma unroll
  for (int i=0;i<12;++i){ int c = lane + i*64; o[c] = (v[i]-mu)*rs*g[c] + be[c]; }
}

extern "C" void kernel_launch(void* const* d_in, const int* in_sizes, int n_in,
                              void* d_out, int out_size, void* d_ws, size_t ws_size,
                              hipStream_t stream)
{
  (void)in_sizes; (void)n_in; (void)out_size; (void)ws_size;
  const float* x     = (const float*)d_in[0];
  const float* w1[3] = {(const float*)d_in[1], (const float*)d_in[5], (const float*)d_in[9]};
  const float* b1[3] = {(const float*)d_in[2], (const float*)d_in[6], (const float*)d_in[10]};
  const float* w2[3] = {(const float*)d_in[3], (const float*)d_in[7], (const float*)d_in[11]};
  const float* b2[3] = {(const float*)d_in[4], (const float*)d_in[8], (const float*)d_in[12]};
  const float* lnw = (const float*)d_in[13];
  const float* lnb = (const float*)d_in[14];

  char* ws = (char*)d_ws;
  size_t off = 0;
  auto alloc = [&](size_t bytes)->void* {
    void* p = ws + off; off += (bytes + 255) & ~size_t(255); return p;
  };
  f16* xh  = (f16*)alloc((size_t)MM*NE*2);   // reused as sb after layer-1
  f16* Ha  = (f16*)alloc((size_t)MM*N3*2);   // reused as y after layer-2
  f16* qh  = (f16*)alloc((size_t)MM*NE*2);
  f16* kh  = (f16*)alloc((size_t)MM*NE*2);
  f16* vt  = (f16*)alloc((size_t)MM*NE*2);   // [NB][NE][TT]
  f16* wt1 = (f16*)alloc((size_t)N3*NE*2);
  f16* wt2 = (f16*)alloc((size_t)N3*NE*2);
  float* b1a = (float*)alloc((size_t)N3*4);
  float* b2a = (float*)alloc((size_t)N3*4);
  f16*   sb  = xh;
  float* y   = (float*)Ha;

  cvt_f16_k<<<(MM*NE/4 + 255)/256, 256, 0, stream>>>(x, xh, MM*NE);
  transpose_w6_k<<<dim3(NE/32, NE/32, 6), 256, 0, stream>>>(
      w1[0], w1[1], w1[2], w2[0], w2[1], w2[2], wt1, wt2);
  packb_k<<<18, 256, 0, stream>>>(b1[0], b1[1], b1[2], b2[0], b2[1], b2[2], b1a, b2a);

  gemm_l1_k<<<dim3(MM/128 * N3/128), 256, 0, stream>>>(xh, wt1, b1a, Ha);
  gemm_l2_k<<<dim3(MM/128 * NE/128, 1, 3), 256, 0, stream>>>(Ha, wt2, b2a, qh, kh, vt);

  attn_qk_k<<<dim3(TT/64, NB), 256, 0, stream>>>(qh, kh, sb);
  attn_pv_k<<<dim3(TT/64, NE/64, NB), 256, 0, stream>>>(sb, vt, y);
  layernorm_k<<<MM/4, 256, 0, stream>>>(y, lnw, lnb, (float*)d_out);
}

// Round 6
// 371.836 us; speedup vs baseline: 1.3814x; 1.0981x over previous
//
#include <hip/hip_runtime.h>

typedef _Float16 f16;
typedef _Float16 half8 __attribute__((ext_vector_type(8)));
typedef float float4v __attribute__((ext_vector_type(4)));

#define NE 768
#define N3 2304
#define TT 4096
#define NB 4
#define MM (NB*TT)
#define SPAN 256
#define JW 320
#define SLDS 328

#define GLDS(g, l) __builtin_amdgcn_global_load_lds( \
    (const __attribute__((address_space(1))) void*)(g), \
    (__attribute__((address_space(3))) void*)(l), 16, 0, 0)

#define VMW(n) asm volatile("s_waitcnt vmcnt(" #n ")" ::: "memory")
#define SBAR() __builtin_amdgcn_s_barrier()
#define SCHED0() __builtin_amdgcn_sched_barrier(0)

__device__ __forceinline__ float gelu_exact(float v){
  return 0.5f * v * (1.0f + erff(v * 0.70710678118654752440f));
}

struct alignas(8) H4 { f16 a,b,c,d; };

// ---------------- prep kernels ----------------
__global__ __launch_bounds__(256) void cvt_f16_k(const float* __restrict__ in,
                                                 f16* __restrict__ out, int n){
  int i = (blockIdx.x*256 + threadIdx.x)*4;
  if (i >= n) return;
  float4 v = *(const float4*)(in + i);
  H4 o; o.a=(f16)v.x; o.b=(f16)v.y; o.c=(f16)v.z; o.d=(f16)v.w;
  *(H4*)(out + i) = o;
}

__global__ __launch_bounds__(256) void transpose_w6_k(
    const float* __restrict__ w0, const float* __restrict__ w1,
    const float* __restrict__ w2, const float* __restrict__ w3,
    const float* __restrict__ w4, const float* __restrict__ w5,
    f16* __restrict__ wt1, f16* __restrict__ wt2){
  __shared__ float tile[32][33];
  int z = blockIdx.z;
  const float* W = z==0?w0 : z==1?w1 : z==2?w2 : z==3?w3 : z==4?w4 : w5;
  f16* Wt = (z<3 ? wt1 + (size_t)z*NE*NE : wt2 + (size_t)(z-3)*NE*NE);
  int tx = threadIdx.x & 31, ty = threadIdx.x >> 5;
  int bx = blockIdx.x * 32, by = blockIdx.y * 32;
  #pragma unroll
  for (int r=0;r<32;r+=8) tile[ty+r][tx] = W[(size_t)(by+ty+r)*NE + bx + tx];
  __syncthreads();
  #pragma unroll
  for (int r=0;r<32;r+=8) Wt[(size_t)(bx+ty+r)*NE + by + tx] = (f16)tile[tx][ty+r];
}

__global__ void packb_k(const float* __restrict__ a0, const float* __restrict__ a1,
                        const float* __restrict__ a2, const float* __restrict__ c0,
                        const float* __restrict__ c1, const float* __restrict__ c2,
                        float* __restrict__ o1, float* __restrict__ o2){
  int i = blockIdx.x*256 + threadIdx.x;
  if (i < N3){
    const float* s = (i<NE) ? a0 : (i<2*NE ? a1 : a2);
    o1[i] = s[i % NE];
  } else if (i < 2*N3){
    int k = i - N3;
    const float* s = (k<NE) ? c0 : (k<2*NE ? c1 : c2);
    o2[k] = s[k % NE];
  }
}

// ---------------- 128x128 GEMM core, BK=64, double-buffered, counted vmcnt ----------------
__device__ __forceinline__ void gemm_core(
    const f16* __restrict__ A, int lda,
    const f16* __restrict__ Bt, int ldb,
    int brow, int bcol, f16* sh, float4v (&acc)[4][4])
{
  const int tid = threadIdx.x, lane = tid & 63, wave = tid >> 6;
  const int l15 = lane & 15, lk = lane >> 4;
  const int wr = (wave >> 1)*64, wc = (wave & 1)*64;

  const int srow   = wave*8 + (lane >> 3);
  const int schunk = ((lane & 7) ^ (lane >> 3))*8;
  const f16* Asrc = A  + (size_t)(brow + srow)*lda + schunk;
  const f16* Bsrc = Bt + (size_t)(bcol + srow)*ldb + schunk;
  const int wdst = wave*512;

  const int rsw0 = (lk ^ (l15 & 7))*8;
  const int rsw1 = ((4 + lk) ^ (l15 & 7))*8;

#define STAGE(buf, k0) do{ \
    f16* _a = sh + (buf)*16384 + wdst; \
    f16* _b = _a + 8192; \
    const f16* _as = Asrc + (k0); \
    const f16* _bs = Bsrc + (k0); \
    _Pragma("unroll") \
    for (int _t = 0; _t < 4; ++_t){ \
      GLDS(_as + (size_t)(_t*32)*lda, _a + _t*2048); \
      GLDS(_bs + (size_t)(_t*32)*ldb, _b + _t*2048); \
    } }while(0)

  STAGE(0, 0);
  #pragma unroll
  for (int t = 0; t < 12; ++t){
    const f16* Ac = sh + (t & 1)*16384;
    const f16* Bc = Ac + 8192;
    if (t < 11) STAGE((t+1) & 1, (t+1)*64);
    if (t < 11) { VMW(8); } else { VMW(0); }
    SBAR(); SCHED0();
    half8 af0[4], af1[4], bf0[4], bf1[4];
    #pragma unroll
    for (int i=0;i<4;++i){
      const f16* pa = Ac + (wr + i*16 + l15)*64;
      af0[i] = *(const half8*)(pa + rsw0);
      af1[i] = *(const half8*)(pa + rsw1);
      const f16* pb = Bc + (wc + i*16 + l15)*64;
      bf0[i] = *(const half8*)(pb + rsw0);
      bf1[i] = *(const half8*)(pb + rsw1);
    }
    #pragma unroll
    for (int i=0;i<4;++i)
      #pragma unroll
      for (int j=0;j<4;++j)
        acc[i][j] = __builtin_amdgcn_mfma_f32_16x16x32_f16(af0[i], bf0[j], acc[i][j], 0, 0, 0);
    #pragma unroll
    for (int i=0;i<4;++i)
      #pragma unroll
      for (int j=0;j<4;++j)
        acc[i][j] = __builtin_amdgcn_mfma_f32_16x16x32_f16(af1[i], bf1[j], acc[i][j], 0, 0, 0);
    SCHED0(); SBAR();
  }
#undef STAGE
}

// ---------------- layer-1: H_all = gelu(xh @ wt1^T + b1) ----------------
__global__ __launch_bounds__(256) void gemm_l1_k(
    const f16* __restrict__ A, const f16* __restrict__ Bt,
    const float* __restrict__ bias, f16* __restrict__ Out)
{
  __shared__ f16 smem[32768];
  float4v acc[4][4]{};
  const int bid = blockIdx.x;
  const int L = (bid & 7)*288 + (bid >> 3);
  const int brow = (L/18)*128, bcol = (L%18)*128;
  gemm_core(A, NE, Bt, NE, brow, bcol, smem, acc);

  const int tid = threadIdx.x, lane = tid & 63, wave = tid >> 6;
  const int l15 = lane & 15, lk = lane >> 4;
  const int wr = (wave >> 1)*64, wc = (wave & 1)*64;
  #pragma unroll
  for (int j=0;j<4;++j){
    int col = wc + j*16 + l15;
    float bv = bias[bcol + col];
    #pragma unroll
    for (int i=0;i<4;++i){
      #pragma unroll
      for (int r=0;r<4;++r){
        int row = wr + i*16 + lk*4 + r;
        smem[row*128 + (col ^ ((row&7)<<3))] = (f16)gelu_exact(acc[i][j][r] + bv);
      }
    }
  }
  __syncthreads();
  #pragma unroll
  for (int it=0; it<8; ++it){
    int idx = tid + it*256;
    int row = idx >> 4, cc = (idx & 15)*8;
    half8 v = *(const half8*)&smem[row*128 + (cc ^ ((row&7)<<3))];
    *(half8*)(Out + (size_t)(brow + row)*N3 + bcol + cc) = v;
  }
}

// ---------------- layer-2 (z=0,1,2): q/k row-major, v transposed ----------------
__global__ __launch_bounds__(256) void gemm_l2_k(
    const f16* __restrict__ H, const f16* __restrict__ wt2_all,
    const float* __restrict__ b2_all,
    f16* __restrict__ qh, f16* __restrict__ kh, f16* __restrict__ vt)
{
  __shared__ f16 smem[32768];
  float4v acc[4][4]{};
  const int z = blockIdx.z;
  const int bid = blockIdx.x;
  const int L = (bid & 7)*96 + (bid >> 3);
  const int brow = (L/6)*128, bcol = (L%6)*128;
  gemm_core(H + z*NE, N3, wt2_all + (size_t)z*NE*NE, NE, brow, bcol, smem, acc);

  const float* bias = b2_all + z*NE;
  const int tid = threadIdx.x, lane = tid & 63, wave = tid >> 6;
  const int l15 = lane & 15, lk = lane >> 4;
  const int wr = (wave >> 1)*64, wc = (wave & 1)*64;

  if (z < 2){
    f16* Out = z ? kh : qh;
    #pragma unroll
    for (int j=0;j<4;++j){
      int col = wc + j*16 + l15;
      float bv = bias[bcol + col];
      #pragma unroll
      for (int i=0;i<4;++i){
        #pragma unroll
        for (int r=0;r<4;++r){
          int row = wr + i*16 + lk*4 + r;
          smem[row*128 + (col ^ ((row&7)<<3))] = (f16)(acc[i][j][r] + bv);
        }
      }
    }
    __syncthreads();
    #pragma unroll
    for (int it=0; it<8; ++it){
      int idx = tid + it*256;
      int row = idx >> 4, cc = (idx & 15)*8;
      half8 v = *(const half8*)&smem[row*128 + (cc ^ ((row&7)<<3))];
      *(half8*)(Out + (size_t)(brow + row)*NE + bcol + cc) = v;
    }
  } else {
    #pragma unroll
    for (int j=0;j<4;++j){
      int cl = wc + j*16 + l15;
      float bv = bias[bcol + cl];
      #pragma unroll
      for (int i=0;i<4;++i){
        int r0 = wr + i*16 + lk*4;
        H4 p; p.a = (f16)(acc[i][j][0] + bv); p.b = (f16)(acc[i][j][1] + bv);
              p.c = (f16)(acc[i][j][2] + bv); p.d = (f16)(acc[i][j][3] + bv);
        *(H4*)&smem[cl*128 + (r0 ^ ((cl&7)<<3))] = p;
      }
    }
    __syncthreads();
    int b = brow / TT, t0 = brow % TT;
    #pragma unroll
    for (int it=0; it<8; ++it){
      int idx = tid + it*256;
      int col = idx >> 4, rc = (idx & 15)*8;
      half8 v = *(const half8*)&smem[col*128 + (rc ^ ((col&7)<<3))];
      *(half8*)(vt + (size_t)b*NE*TT + (size_t)(bcol + col)*TT + t0 + rc) = v;
    }
  }
}

// ---------------- fused banded attention: S = mask.*(QK^T)/c in LDS, Y = S.V ----------------
// Block = (q-tile of 64 rows, batch). 4 waves.
// Phase 1: waves split j-frags (5 each); Q staged per k-step; T14 reg-prefetch.
// Phase 2: each wave holds its 16 S-rows in regs; V d-chunks staged with T14 prefetch.
__global__ __launch_bounds__(256) void attn_fused_k(
    const f16* __restrict__ Q, const f16* __restrict__ K,
    const f16* __restrict__ Vt, float* __restrict__ Y)
{
  extern __shared__ __align__(16) f16 sh[];
  f16* S  = sh;                       // [64][SLDS]
  f16* Ks = sh + 64*SLDS;             // [320][40]  (phase 1)
  f16* Qs = Ks + 320*40;              // [64][40]   (phase 1)
  f16* Vs = sh + 64*SLDS;             // [64][SLDS] (phase 2, overlays Ks/Qs)

  const int tid = threadIdx.x, lane = tid & 63, wave = tid >> 6;
  const int l15 = lane & 15, lk = lane >> 4;
  const int qt = blockIdx.x, b = blockIdx.y;
  const int rowbase = b*TT + qt*64;
  const int jbase = qt*64 - SPAN;
  const half8 zero{};

  // ---------- phase 1: S ----------
  float4v acc[4][5]{};
  half8 kreg[5], qreg;
  #pragma unroll
  for (int it=0; it<5; ++it){
    int idx = tid + it*256; int r = idx>>2, c = (idx&3)*8; int j = jbase + r;
    kreg[it] = (j>=0) ? *(const half8*)(K + (size_t)(b*TT+j)*NE + c) : zero;
  }
  { int r = tid>>2, c = (tid&3)*8;
    qreg = *(const half8*)(Q + (size_t)(rowbase + r)*NE + c); }

  for (int t=0; t<24; ++t){
    __syncthreads();
    #pragma unroll
    for (int it=0; it<5; ++it){
      int idx = tid + it*256; int r = idx>>2, c = (idx&3)*8;
      *(half8*)&Ks[r*40 + c] = kreg[it];
    }
    { int r = tid>>2, c = (tid&3)*8; *(half8*)&Qs[r*40 + c] = qreg; }
    __syncthreads();
    if (t < 23){
      int k0 = (t+1)*32;
      #pragma unroll
      for (int it=0; it<5; ++it){
        int idx = tid + it*256; int r = idx>>2, c = (idx&3)*8; int j = jbase + r;
        kreg[it] = (j>=0) ? *(const half8*)(K + (size_t)(b*TT+j)*NE + k0 + c) : zero;
      }
      { int r = tid>>2, c = (tid&3)*8;
        qreg = *(const half8*)(Q + (size_t)(rowbase + r)*NE + k0 + c); }
    }
    half8 aq[4];
    #pragma unroll
    for (int i=0;i<4;++i) aq[i] = *(const half8*)&Qs[(i*16 + l15)*40 + lk*8];
    #pragma unroll
    for (int fl=0; fl<5; ++fl){
      half8 bk = *(const half8*)&Ks[((wave*5 + fl)*16 + l15)*40 + lk*8];
      #pragma unroll
      for (int i=0;i<4;++i)
        acc[i][fl] = __builtin_amdgcn_mfma_f32_16x16x32_f16(aq[i], bk, acc[i][fl], 0, 0, 0);
    }
  }
  // mask + scale -> S in LDS
  const float inv = 1.0f / 443.40500673763256f;   // 1/sqrt(768*256)
  #pragma unroll
  for (int fl=0; fl<5; ++fl){
    int jl = (wave*5 + fl)*16 + l15;
    int jg = jbase + jl;
    #pragma unroll
    for (int i=0;i<4;++i){
      #pragma unroll
      for (int r=0;r<4;++r){
        int iloc = i*16 + lk*4 + r;
        int d = (qt*64 + iloc) - jg;
        float v = (d >= 0 && d < SPAN) ? acc[i][fl][r]*inv : 0.0f;
        S[iloc*SLDS + jl] = (f16)v;
      }
    }
  }
  __syncthreads();

  // ---------- phase 2: Y = S.V ----------
  half8 sreg[10];
  #pragma unroll
  for (int ks=0; ks<10; ++ks)
    sreg[ks] = *(const half8*)&S[(wave*16 + l15)*SLDS + ks*32 + lk*8];

  half8 vreg[10];
  #pragma unroll
  for (int it=0; it<10; ++it){
    int idx = tid + it*256; int dd = idx/40, c = (idx - dd*40)*8; int j = jbase + c;
    vreg[it] = (j>=0) ? *(const half8*)(Vt + ((size_t)b*NE + dd)*TT + j) : zero;
  }
  for (int cc=0; cc<12; ++cc){
    __syncthreads();
    #pragma unroll
    for (int it=0; it<10; ++it){
      int idx = tid + it*256; int dd = idx/40, c = (idx - dd*40)*8;
      *(half8*)&Vs[dd*SLDS + c] = vreg[it];
    }
    __syncthreads();
    if (cc < 11){
      int d0n = (cc+1)*64;
      #pragma unroll
      for (int it=0; it<10; ++it){
        int idx = tid + it*256; int dd = idx/40, c = (idx - dd*40)*8; int j = jbase + c;
        vreg[it] = (j>=0) ? *(const half8*)(Vt + ((size_t)b*NE + d0n + dd)*TT + j) : zero;
      }
    }
    float4v py[4]{};
    #pragma unroll
    for (int ks=0; ks<10; ++ks){
      #pragma unroll
      for (int fl=0; fl<4; ++fl){
        half8 bv = *(const half8*)&Vs[(fl*16 + l15)*SLDS + ks*32 + lk*8];
        py[fl] = __builtin_amdgcn_mfma_f32_16x16x32_f16(sreg[ks], bv, py[fl], 0, 0, 0);
      }
    }
    int d0 = cc*64;
    #pragma unroll
    for (int fl=0; fl<4; ++fl){
      #pragma unroll
      for (int r=0;r<4;++r){
        Y[(size_t)(rowbase + wave*16 + lk*4 + r)*NE + d0 + fl*16 + l15] = py[fl][r];
      }
    }
  }
}

// ---------------- LayerNorm ----------------
__global__ __launch_bounds__(256) void layernorm_k(
    const float* __restrict__ Y, const float* __restrict__ g,
    const float* __restrict__ be, float* __restrict__ Out)
{
  int row  = blockIdx.x*4 + (threadIdx.x >> 6);
  int lane = threadIdx.x & 63;
  const float* y = Y + (size_t)row*NE;
  float v[12], s=0.f, s2=0.f;
  #pragma unroll
  for (int i=0;i<12;++i){ v[i] = y[lane + i*64]; s += v[i]; s2 += v[i]*v[i]; }
  #pragma unroll
  for (int m=32;m>=1;m>>=1){ s += __shfl_xor(s,m,64); s2 += __shfl_xor(s2,m,64); }
  float mu  = s*(1.f/NE);
  float var = s2*(1.f/NE) - mu*mu;
  float rs  = rsqrtf(var + 1e-5f);
  float* o = Out + (size_t)row*NE;
  #pragma unroll
  for (int i=0;i<12;++i){ int c = lane + i*64; o[c] = (v[i]-mu)*rs*g[c] + be[c]; }
}

extern "C" void kernel_launch(void* const* d_in, const int* in_sizes, int n_in,
                              void* d_out, int out_size, void* d_ws, size_t ws_size,
                              hipStream_t stream)
{
  (void)in_sizes; (void)n_in; (void)out_size; (void)ws_size;
  const float* x     = (const float*)d_in[0];
  const float* w1[3] = {(const float*)d_in[1], (const float*)d_in[5], (const float*)d_in[9]};
  const float* b1[3] = {(const float*)d_in[2], (const float*)d_in[6], (const float*)d_in[10]};
  const float* w2[3] = {(const float*)d_in[3], (const float*)d_in[7], (const float*)d_in[11]};
  const float* b2[3] = {(const float*)d_in[4], (const float*)d_in[8], (const float*)d_in[12]};
  const float* lnw = (const float*)d_in[13];
  const float* lnb = (const float*)d_in[14];

  char* ws = (char*)d_ws;
  size_t off = 0;
  auto alloc = [&](size_t bytes)->void* {
    void* p = ws + off; off += (bytes + 255) & ~size_t(255); return p;
  };
  f16* xh  = (f16*)alloc((size_t)MM*NE*2);
  f16* Ha  = (f16*)alloc((size_t)MM*N3*2);   // reused as y after layer-2
  f16* qh  = (f16*)alloc((size_t)MM*NE*2);
  f16* kh  = (f16*)alloc((size_t)MM*NE*2);
  f16* vt  = (f16*)alloc((size_t)MM*NE*2);   // [NB][NE][TT]
  f16* wt1 = (f16*)alloc((size_t)N3*NE*2);
  f16* wt2 = (f16*)alloc((size_t)N3*NE*2);
  float* b1a = (float*)alloc((size_t)N3*4);
  float* b2a = (float*)alloc((size_t)N3*4);
  float* y   = (float*)Ha;

  hipFuncSetAttribute(reinterpret_cast<const void*>(&attn_fused_k),
                      hipFuncAttributeMaxDynamicSharedMemorySize, 83968);

  cvt_f16_k<<<(MM*NE/4 + 255)/256, 256, 0, stream>>>(x, xh, MM*NE);
  transpose_w6_k<<<dim3(NE/32, NE/32, 6), 256, 0, stream>>>(
      w1[0], w1[1], w1[2], w2[0], w2[1], w2[2], wt1, wt2);
  packb_k<<<18, 256, 0, stream>>>(b1[0], b1[1], b1[2], b2[0], b2[1], b2[2], b1a, b2a);

  gemm_l1_k<<<dim3(MM/128 * N3/128), 256, 0, stream>>>(xh, wt1, b1a, Ha);
  gemm_l2_k<<<dim3(MM/128 * NE/128, 1, 3), 256, 0, stream>>>(Ha, wt2, b2a, qh, kh, vt);

  attn_fused_k<<<dim3(TT/64, NB), 256, 83968, stream>>>(qh, kh, vt, y);
  layernorm_k<<<MM/4, 256, 0, stream>>>(y, lnw, lnb, (float*)d_out);
}